// Round 10
// baseline (441.977 us; speedup 1.0000x reference)
//
#include <hip/hip_runtime.h>
#include <hip/hip_bf16.h>
#include <math.h>

#define B_DIM 64
#define T_DIM 512
#define D_DIM 1024
#define TT (T_DIM * T_DIM)   // 262144
#define TD (T_DIM * D_DIM)   // 524288
#define PSTR ((long)B_DIM * T_DIM)  // 32768: stride between the 2 softmax partials

typedef _Float16 f16;
typedef f16 f16x4 __attribute__((ext_vector_type(4)));
typedef f16 f16x8 __attribute__((ext_vector_type(8)));
typedef float f32x4 __attribute__((ext_vector_type(4)));

__device__ __forceinline__ void gld_lds16(const void* g, void* l) {
    __builtin_amdgcn_global_load_lds(
        (const __attribute__((address_space(1))) void*)g,
        (__attribute__((address_space(3))) void*)l, 16, 0, 0);
}

// LDS[r][j] holds global k-chunk (j ^ ((r>>1)&3)); conflict-free ds_read_b128.
#define SWZ(r) (((r) >> 1) & 3)

// ===========================================================================
// D1: pure streaming casts (high occupancy: 256 thr, 9KB LDS)
//   z<64: q1 tile -> q1ht (transpose-cast);  z<128: q2 -> q2ht;  z==128: U -> Uht
// ===========================================================================
__global__ __launch_bounds__(256) void k_cast(const float* __restrict__ q1,
                                              f16* __restrict__ q1ht,
                                              const float* __restrict__ q2,
                                              f16* __restrict__ q2ht,
                                              const float* __restrict__ U,
                                              f16* __restrict__ Uht) {
    __shared__ f16 tr[64][72];
    int tid = threadIdx.x;
    int z = blockIdx.z;
    if (z < 128) {
        const float* src = (z < 64) ? q1 : q2;
        f16* dstT = (z < 64) ? q1ht : q2ht;
        int b = z & 63;
        int d0 = blockIdx.x * 64, t0 = blockIdx.y * 64;
        const float* S = src + ((size_t)b * T_DIM + t0) * D_DIM + d0;
        int rr = tid >> 4, cc = (tid & 15) * 4;
#pragma unroll
        for (int i = 0; i < 4; ++i) {
            int r = rr + i * 16;
            float4 v = *(const float4*)(S + (size_t)r * D_DIM + cc);
            tr[cc + 0][r] = (f16)v.x;
            tr[cc + 1][r] = (f16)v.y;
            tr[cc + 2][r] = (f16)v.z;
            tr[cc + 3][r] = (f16)v.w;
        }
        __syncthreads();
        f16* Dt = dstT + ((size_t)b * D_DIM + d0) * T_DIM + t0;
        int r2 = tid >> 3, c8 = (tid & 7) * 8;
#pragma unroll
        for (int i = 0; i < 2; ++i) {
            int d = r2 + i * 32;
            f16x8 vv = *(const f16x8*)(&tr[d][c8]);
            *(f16x8*)(Dt + (size_t)d * T_DIM + c8) = vv;
        }
    } else {
        int pos = blockIdx.y * 16 + blockIdx.x;   // 0..127
        for (int u = 0; u < 2; ++u) {
            int tile = pos + u * 128;             // 0..255
            int n0 = (tile & 15) * 64, k0 = (tile >> 4) * 64;
            int rr = tid >> 4, cc = (tid & 15) * 4;
#pragma unroll
            for (int i = 0; i < 4; ++i) {
                int r = rr + i * 16;
                float4 v = *(const float4*)(U + (size_t)(k0 + r) * D_DIM + n0 + cc);
                tr[cc + 0][r] = (f16)v.x;
                tr[cc + 1][r] = (f16)v.y;
                tr[cc + 2][r] = (f16)v.z;
                tr[cc + 3][r] = (f16)v.w;
            }
            __syncthreads();
            int r2 = tid >> 3, c8 = (tid & 7) * 8;
#pragma unroll
            for (int i = 0; i < 2; ++i) {
                int n = r2 + i * 32;
                f16x8 vv = *(const f16x8*)(&tr[n][c8]);
                *(f16x8*)(Uht + (size_t)(n0 + n) * D_DIM + k0 + c8) = vv;
            }
            __syncthreads();
        }
    }
}

// ===========================================================================
// D2: GEMM1 alone: qUh = cast(q1) @ Uht^T, A reg-staged from f32.
// grid (4,128) -> 512 blocks, full machine.
// ===========================================================================
__global__ __launch_bounds__(512, 2) void k_gemm1(const float* __restrict__ q1,
                                                  const f16* __restrict__ Uht,
                                                  f16* __restrict__ qUh) {
    __shared__ __align__(16) f16 LA[2][8192];
    __shared__ __align__(16) f16 LB[2][8192];
    const int tid = threadIdx.x;
    const int lane = tid & 63, w = tid >> 6;
    int o = blockIdx.x + 4 * blockIdx.y;          // 0..511
    int fl = (o & 7) * 64 + (o >> 3);             // XCD swizzle, nwg=512
    int bx = fl & 3, by = fl >> 2;
    const float* Aq = q1 + (long)(by * 256) * D_DIM;
    const f16* Bb = Uht + (long)(bx * 256) * D_DIM;

    const int r0 = tid >> 2, j0 = tid & 3;
    const int r1 = r0 + 128;
    const long srcA0 = (long)r0 * D_DIM + j0 * 8;
    const long srcA1 = (long)r1 * D_DIM + j0 * 8;
    const int wA0 = r0 * 32 + ((j0 ^ SWZ(r0)) << 3);
    const int wA1 = r1 * 32 + ((j0 ^ SWZ(r1)) << 3);
    const long offB0 = (long)r0 * D_DIM + (j0 ^ SWZ(r0)) * 8;
    const long offB1 = (long)r1 * D_DIM + (j0 ^ SWZ(r1)) * 8;
    const int ldsOff0 = w * 512, ldsOff1 = 4096 + w * 512;
    const int g = lane >> 4;
    const int rA0 = (w & 1) * 128 + (lane & 15);
    const int rB0 = (w >> 1) * 64 + (lane & 15);

    f32x4 acc[8][4] = {};
    {
        float4 v0 = *(const float4*)(Aq + srcA0);
        float4 v1 = *(const float4*)(Aq + srcA0 + 4);
        float4 v2 = *(const float4*)(Aq + srcA1);
        float4 v3 = *(const float4*)(Aq + srcA1 + 4);
        f16x8 h0 = {(f16)v0.x, (f16)v0.y, (f16)v0.z, (f16)v0.w,
                    (f16)v1.x, (f16)v1.y, (f16)v1.z, (f16)v1.w};
        f16x8 h1 = {(f16)v2.x, (f16)v2.y, (f16)v2.z, (f16)v2.w,
                    (f16)v3.x, (f16)v3.y, (f16)v3.z, (f16)v3.w};
        *(f16x8*)(&LA[0][wA0]) = h0;
        *(f16x8*)(&LA[0][wA1]) = h1;
        gld_lds16(Bb + offB0, &LB[0][ldsOff0]);
        gld_lds16(Bb + offB1, &LB[0][ldsOff1]);
    }
    __syncthreads();

    for (int t = 0; t < 32; ++t) {
        const int cur = t & 1;
        float4 v0, v1, v2, v3;
        if (t + 1 < 32) {
            const long kc = (long)(t + 1) << 5;
            v0 = *(const float4*)(Aq + srcA0 + kc);
            v1 = *(const float4*)(Aq + srcA0 + kc + 4);
            v2 = *(const float4*)(Aq + srcA1 + kc);
            v3 = *(const float4*)(Aq + srcA1 + kc + 4);
            gld_lds16(Bb + offB0 + kc, &LB[cur ^ 1][ldsOff0]);
            gld_lds16(Bb + offB1 + kc, &LB[cur ^ 1][ldsOff1]);
        }
        f16x8 a[8], b[4];
#pragma unroll
        for (int m = 0; m < 8; ++m) {
            int r = rA0 + m * 16;
            a[m] = *(const f16x8*)(&LA[cur][r * 32 + ((g ^ SWZ(r)) << 3)]);
        }
#pragma unroll
        for (int n = 0; n < 4; ++n) {
            int r = rB0 + n * 16;
            b[n] = *(const f16x8*)(&LB[cur][r * 32 + ((g ^ SWZ(r)) << 3)]);
        }
        __builtin_amdgcn_s_setprio(1);
#pragma unroll
        for (int m = 0; m < 8; ++m)
#pragma unroll
            for (int n = 0; n < 4; ++n)
                acc[m][n] = __builtin_amdgcn_mfma_f32_16x16x32_f16(a[m], b[n], acc[m][n], 0, 0, 0);
        __builtin_amdgcn_s_setprio(0);
        if (t + 1 < 32) {
            f16x8 h0 = {(f16)v0.x, (f16)v0.y, (f16)v0.z, (f16)v0.w,
                        (f16)v1.x, (f16)v1.y, (f16)v1.z, (f16)v1.w};
            f16x8 h1 = {(f16)v2.x, (f16)v2.y, (f16)v2.z, (f16)v2.w,
                        (f16)v3.x, (f16)v3.y, (f16)v3.z, (f16)v3.w};
            *(f16x8*)(&LA[cur ^ 1][wA0]) = h0;
            *(f16x8*)(&LA[cur ^ 1][wA1]) = h1;
        }
        __syncthreads();
    }
    const int row0 = by * 256 + (w & 1) * 128 + (lane >> 4) * 4;
    const int col0 = bx * 256 + (w >> 1) * 64 + (lane & 15);
#pragma unroll
    for (int m = 0; m < 8; ++m)
#pragma unroll
        for (int r = 0; r < 4; ++r) {
            long row = row0 + m * 16 + r;
#pragma unroll
            for (int n = 0; n < 4; ++n)
                qUh[row * D_DIM + col0 + n * 16] = (f16)acc[m][n][r];
        }
}

// ===========================================================================
// D3: att GEMM (qUh @ cast(q2)^T); A via gld_lds (f16), B reg-staged from
// q2 f32 (natural [s][e] layout, L3-resident from D1). Epilogue: relu,
// rowP/colP partials, P2'[t][s]=exp(att-M_rowhalf), P1'[s][t]=exp(att-M_colhalf).
// grid (2,2,64)
// ===========================================================================
__global__ __launch_bounds__(512, 2) void k_att3(const f16* __restrict__ qUh,
                                                 const float* __restrict__ q2,
                                                 f16* __restrict__ P2,
                                                 f16* __restrict__ P1,
                                                 float2* __restrict__ rowP,
                                                 float2* __restrict__ colP) {
    __shared__ __align__(16) f16 LA[2][8192];
    __shared__ __align__(16) f16 LB[2][8192];
    const int tid = threadIdx.x;
    const int lane = tid & 63, w = tid >> 6;

    int o = blockIdx.x + 2 * (blockIdx.y + 2 * blockIdx.z);  // nwg=256
    int fl = (o & 7) * 32 + (o >> 3);
    const int bx = fl & 1, by = (fl >> 1) & 1, zb = fl >> 2;

    const f16* Ab = qUh + (long)(zb * 512 + by * 256) * D_DIM;
    const float* Bq = q2 + (long)zb * TD + (long)(bx * 256) * D_DIM;

    const int r0 = tid >> 2, j0 = tid & 3;
    const int r1 = r0 + 128;
    const long offA0 = (long)r0 * D_DIM + (j0 ^ SWZ(r0)) * 8;
    const long offA1 = (long)r1 * D_DIM + (j0 ^ SWZ(r1)) * 8;
    const long srcB0 = (long)r0 * D_DIM + j0 * 8;
    const long srcB1 = (long)r1 * D_DIM + j0 * 8;
    const int wB0 = r0 * 32 + ((j0 ^ SWZ(r0)) << 3);
    const int wB1 = r1 * 32 + ((j0 ^ SWZ(r1)) << 3);
    const int ldsOff0 = w * 512, ldsOff1 = 4096 + w * 512;
    const int g = lane >> 4;
    const int rA0 = (w & 1) * 128 + (lane & 15);
    const int rB0 = (w >> 1) * 64 + (lane & 15);

    f32x4 acc[8][4] = {};

    {
        gld_lds16(Ab + offA0, &LA[0][ldsOff0]);
        gld_lds16(Ab + offA1, &LA[0][ldsOff1]);
        float4 v0 = *(const float4*)(Bq + srcB0);
        float4 v1 = *(const float4*)(Bq + srcB0 + 4);
        float4 v2 = *(const float4*)(Bq + srcB1);
        float4 v3 = *(const float4*)(Bq + srcB1 + 4);
        f16x8 h0 = {(f16)v0.x, (f16)v0.y, (f16)v0.z, (f16)v0.w,
                    (f16)v1.x, (f16)v1.y, (f16)v1.z, (f16)v1.w};
        f16x8 h1 = {(f16)v2.x, (f16)v2.y, (f16)v2.z, (f16)v2.w,
                    (f16)v3.x, (f16)v3.y, (f16)v3.z, (f16)v3.w};
        *(f16x8*)(&LB[0][wB0]) = h0;
        *(f16x8*)(&LB[0][wB1]) = h1;
    }
    __syncthreads();

    for (int t = 0; t < 32; ++t) {
        const int cur = t & 1;
        float4 v0, v1, v2, v3;
        if (t + 1 < 32) {
            const long kt = (long)(t + 1) << 5;
            gld_lds16(Ab + offA0 + kt, &LA[cur ^ 1][ldsOff0]);
            gld_lds16(Ab + offA1 + kt, &LA[cur ^ 1][ldsOff1]);
            v0 = *(const float4*)(Bq + srcB0 + kt);
            v1 = *(const float4*)(Bq + srcB0 + kt + 4);
            v2 = *(const float4*)(Bq + srcB1 + kt);
            v3 = *(const float4*)(Bq + srcB1 + kt + 4);
        }
        f16x8 a[8], b[4];
#pragma unroll
        for (int m = 0; m < 8; ++m) {
            int r = rA0 + m * 16;
            a[m] = *(const f16x8*)(&LA[cur][r * 32 + ((g ^ SWZ(r)) << 3)]);
        }
#pragma unroll
        for (int n = 0; n < 4; ++n) {
            int r = rB0 + n * 16;
            b[n] = *(const f16x8*)(&LB[cur][r * 32 + ((g ^ SWZ(r)) << 3)]);
        }
        __builtin_amdgcn_s_setprio(1);
#pragma unroll
        for (int m = 0; m < 8; ++m)
#pragma unroll
            for (int n = 0; n < 4; ++n)
                acc[m][n] = __builtin_amdgcn_mfma_f32_16x16x32_f16(a[m], b[n], acc[m][n], 0, 0, 0);
        __builtin_amdgcn_s_setprio(0);
        if (t + 1 < 32) {
            f16x8 h0 = {(f16)v0.x, (f16)v0.y, (f16)v0.z, (f16)v0.w,
                        (f16)v1.x, (f16)v1.y, (f16)v1.z, (f16)v1.w};
            f16x8 h1 = {(f16)v2.x, (f16)v2.y, (f16)v2.z, (f16)v2.w,
                        (f16)v3.x, (f16)v3.y, (f16)v3.z, (f16)v3.w};
            *(f16x8*)(&LB[cur ^ 1][wB0]) = h0;
            *(f16x8*)(&LB[cur ^ 1][wB1]) = h1;
        }
        __syncthreads();
    }

    // relu
#pragma unroll
    for (int m = 0; m < 8; ++m)
#pragma unroll
        for (int n = 0; n < 4; ++n)
#pragma unroll
            for (int r = 0; r < 4; ++r)
                acc[m][n][r] = fmaxf(acc[m][n][r], 0.0f);

    // ---- softmax partials (LA reused as scratch) ----
    float* redR = (float*)(&LA[0][0]);   // [256][4][2]
    float* redC = redR + 2048;           // [2][256][2]
    float* rowM = redC + 1024;           // [256]
    float* colM = rowM + 256;            // [256]
    const int h = w & 1, cw = w >> 1;
#pragma unroll
    for (int m = 0; m < 8; ++m)
#pragma unroll
        for (int r = 0; r < 4; ++r) {
            float mx = fmaxf(fmaxf(acc[m][0][r], acc[m][1][r]),
                             fmaxf(acc[m][2][r], acc[m][3][r]));
            mx = fmaxf(mx, __shfl_xor(mx, 1));
            mx = fmaxf(mx, __shfl_xor(mx, 2));
            mx = fmaxf(mx, __shfl_xor(mx, 4));
            mx = fmaxf(mx, __shfl_xor(mx, 8));
            float sm = __expf(acc[m][0][r] - mx) + __expf(acc[m][1][r] - mx)
                     + __expf(acc[m][2][r] - mx) + __expf(acc[m][3][r] - mx);
            sm += __shfl_xor(sm, 1);
            sm += __shfl_xor(sm, 2);
            sm += __shfl_xor(sm, 4);
            sm += __shfl_xor(sm, 8);
            if ((lane & 15) == 0) {
                int lr = m * 16 + (lane >> 4) * 4 + r;
                redR[((h * 128 + lr) * 4 + cw) * 2 + 0] = mx;
                redR[((h * 128 + lr) * 4 + cw) * 2 + 1] = sm;
            }
        }
#pragma unroll
    for (int n = 0; n < 4; ++n) {
        float mx = acc[0][n][0];
#pragma unroll
        for (int m = 0; m < 8; ++m)
#pragma unroll
            for (int r = 0; r < 4; ++r) mx = fmaxf(mx, acc[m][n][r]);
        mx = fmaxf(mx, __shfl_xor(mx, 16));
        mx = fmaxf(mx, __shfl_xor(mx, 32));
        float sm = 0.f;
#pragma unroll
        for (int m = 0; m < 8; ++m)
#pragma unroll
            for (int r = 0; r < 4; ++r) sm += __expf(acc[m][n][r] - mx);
        sm += __shfl_xor(sm, 16);
        sm += __shfl_xor(sm, 32);
        if (lane < 16) {
            int c = cw * 64 + n * 16 + lane;
            redC[(h * 256 + c) * 2 + 0] = mx;
            redC[(h * 256 + c) * 2 + 1] = sm;
        }
    }
    __syncthreads();
    if (tid < 256) {
        float M = -1e30f, S = 0.f;
#pragma unroll
        for (int i = 0; i < 4; ++i) {
            float m_ = redR[(tid * 4 + i) * 2 + 0];
            float s_ = redR[(tid * 4 + i) * 2 + 1];
            float nm = fmaxf(M, m_);
            S = S * __expf(M - nm) + s_ * __expf(m_ - nm);
            M = nm;
        }
        rowP[(long)bx * PSTR + (long)zb * 512 + by * 256 + tid] = make_float2(M, S);
        rowM[tid] = M;
    } else {
        int c = tid - 256;
        float m0_ = redC[c * 2 + 0], s0_ = redC[c * 2 + 1];
        float m1_ = redC[(256 + c) * 2 + 0], s1_ = redC[(256 + c) * 2 + 1];
        float M = fmaxf(m0_, m1_);
        float S = s0_ * __expf(m0_ - M) + s1_ * __expf(m1_ - M);
        colP[(long)by * PSTR + (long)zb * 512 + bx * 256 + c] = make_float2(M, S);
        colM[c] = M;
    }
    __syncthreads();

    // ---- P2'[t][s] = f16(exp(att - M_rowhalf)) ----
    f16* P2b = P2 + (long)zb * TT;
#pragma unroll
    for (int m = 0; m < 8; ++m)
#pragma unroll
        for (int r = 0; r < 4; ++r) {
            int Lr = h * 128 + m * 16 + (lane >> 4) * 4 + r;
            float M = rowM[Lr];
            long base = (long)(by * 256 + Lr) * T_DIM + bx * 256;
#pragma unroll
            for (int n = 0; n < 4; ++n) {
                int c = cw * 64 + n * 16 + (lane & 15);
                P2b[base + c] = (f16)__expf(acc[m][n][r] - M);
            }
        }
    // ---- P1'[s][t] = f16(exp(att - M_colhalf)), 8B column stores ----
    f16* P1b = P1 + (long)zb * TT;
#pragma unroll
    for (int m = 0; m < 8; ++m) {
        int Lt = h * 128 + m * 16 + (lane >> 4) * 4;
#pragma unroll
        for (int n = 0; n < 4; ++n) {
            int Lc = cw * 64 + n * 16 + (lane & 15);
            float M = colM[Lc];
            f16x4 v = {(f16)__expf(acc[m][n][0] - M), (f16)__expf(acc[m][n][1] - M),
                       (f16)__expf(acc[m][n][2] - M), (f16)__expf(acc[m][n][3] - M)};
            *(f16x4*)(&P1b[(long)(bx * 256 + Lc) * T_DIM + by * 256 + Lt]) = v;
        }
    }
}

// ===========================================================================
// D4: both align GEMMs in one dispatch. z<64: q2align (P2', q2ht, rowP);
// z>=64: q1align (P1', q1ht, colP). A reg-staged f16 with rescale factor
// exp(M_half - M_global) per (row, k-half); epilogue * 1/S.
// grid (4,2,128)
// ===========================================================================
__global__ __launch_bounds__(512, 2) void k_align(
        const f16* __restrict__ P2, const f16* __restrict__ q2ht,
        const float2* __restrict__ rowP, float* __restrict__ outQ2,
        const f16* __restrict__ P1, const f16* __restrict__ q1ht,
        const float2* __restrict__ colP, float* __restrict__ outQ1) {
    __shared__ __align__(16) f16 LA[2][8192];
    __shared__ __align__(16) f16 LB[2][8192];
    const int tid = threadIdx.x;
    const int lane = tid & 63, w = tid >> 6;

    int o = blockIdx.x + 4 * (blockIdx.y + 2 * blockIdx.z);  // nwg=1024
    int fl = (o & 7) * 128 + (o >> 3);
    const int bx = fl & 3, by = (fl >> 2) & 1, z = fl >> 3;
    const int zb = z & 63;

    const f16* P  = (z < 64) ? P2 : P1;
    const f16* Bt = (z < 64) ? q2ht : q1ht;
    const float2* sp = ((z < 64) ? rowP : colP) + (long)zb * 512;
    float* out = ((z < 64) ? outQ2 : outQ1) + (long)zb * TD;

    const f16* Ab = P + (long)zb * TT + (long)(by * 256) * T_DIM;
    const f16* Bb = Bt + (long)zb * TD + (long)(bx * 256) * T_DIM;

    const int r0 = tid >> 2, j0 = tid & 3;
    const int r1 = r0 + 128;
    // rescale factors: fac(r, k-half) = exp(M_half - M_global)
    float2 pa0 = sp[by * 256 + r0], pb0 = sp[PSTR + by * 256 + r0];
    float M0 = fmaxf(pa0.x, pb0.x);
    f16 f00 = (f16)__expf(pa0.x - M0), f01 = (f16)__expf(pb0.x - M0);
    float2 pa1 = sp[by * 256 + r1], pb1 = sp[PSTR + by * 256 + r1];
    float M1 = fmaxf(pa1.x, pb1.x);
    f16 f10 = (f16)__expf(pa1.x - M1), f11 = (f16)__expf(pb1.x - M1);

    const long srcA0 = (long)r0 * T_DIM + j0 * 8;
    const long srcA1 = (long)r1 * T_DIM + j0 * 8;
    const int wA0 = r0 * 32 + ((j0 ^ SWZ(r0)) << 3);
    const int wA1 = r1 * 32 + ((j0 ^ SWZ(r1)) << 3);
    const long offB0 = (long)r0 * T_DIM + (j0 ^ SWZ(r0)) * 8;
    const long offB1 = (long)r1 * T_DIM + (j0 ^ SWZ(r1)) * 8;
    const int ldsOff0 = w * 512, ldsOff1 = 4096 + w * 512;
    const int g = lane >> 4;
    const int rA0 = (w & 1) * 128 + (lane & 15);
    const int rB0 = (w >> 1) * 64 + (lane & 15);

    f32x4 acc[8][4] = {};
    {
        f16x8 a0 = *(const f16x8*)(Ab + srcA0);
        f16x8 a1 = *(const f16x8*)(Ab + srcA1);
#pragma unroll
        for (int i = 0; i < 8; ++i) { a0[i] *= f00; a1[i] *= f10; }
        *(f16x8*)(&LA[0][wA0]) = a0;
        *(f16x8*)(&LA[0][wA1]) = a1;
        gld_lds16(Bb + offB0, &LB[0][ldsOff0]);
        gld_lds16(Bb + offB1, &LB[0][ldsOff1]);
    }
    __syncthreads();

    for (int t = 0; t < 16; ++t) {
        const int cur = t & 1;
        f16x8 a0n, a1n;
        if (t + 1 < 16) {
            const long kc = (long)(t + 1) << 5;
            a0n = *(const f16x8*)(Ab + srcA0 + kc);
            a1n = *(const f16x8*)(Ab + srcA1 + kc);
            gld_lds16(Bb + offB0 + kc, &LB[cur ^ 1][ldsOff0]);
            gld_lds16(Bb + offB1 + kc, &LB[cur ^ 1][ldsOff1]);
        }
        f16x8 a[8], b[4];
#pragma unroll
        for (int m = 0; m < 8; ++m) {
            int r = rA0 + m * 16;
            a[m] = *(const f16x8*)(&LA[cur][r * 32 + ((g ^ SWZ(r)) << 3)]);
        }
#pragma unroll
        for (int n = 0; n < 4; ++n) {
            int r = rB0 + n * 16;
            b[n] = *(const f16x8*)(&LB[cur][r * 32 + ((g ^ SWZ(r)) << 3)]);
        }
        __builtin_amdgcn_s_setprio(1);
#pragma unroll
        for (int m = 0; m < 8; ++m)
#pragma unroll
            for (int n = 0; n < 4; ++n)
                acc[m][n] = __builtin_amdgcn_mfma_f32_16x16x32_f16(a[m], b[n], acc[m][n], 0, 0, 0);
        __builtin_amdgcn_s_setprio(0);
        if (t + 1 < 16) {
            f16 fa = ((t + 1) & 8) ? f01 : f00;
            f16 fb = ((t + 1) & 8) ? f11 : f10;
#pragma unroll
            for (int i = 0; i < 8; ++i) { a0n[i] *= fa; a1n[i] *= fb; }
            *(f16x8*)(&LA[cur ^ 1][wA0]) = a0n;
            *(f16x8*)(&LA[cur ^ 1][wA1]) = a1n;
        }
        __syncthreads();
    }

    const int row0 = by * 256 + (w & 1) * 128 + (lane >> 4) * 4;
    const int col0 = bx * 256 + (w >> 1) * 64 + (lane & 15);
#pragma unroll
    for (int m = 0; m < 8; ++m)
#pragma unroll
        for (int r = 0; r < 4; ++r) {
            int row = row0 + m * 16 + r;
            float2 pa = sp[row], pb = sp[PSTR + row];
            float M = fmaxf(pa.x, pb.x);
            float S = pa.y * __expf(pa.x - M) + pb.y * __expf(pb.x - M);
            float inv = 1.0f / S;
#pragma unroll
            for (int n = 0; n < 4; ++n)
                out[(long)row * D_DIM + col0 + n * 16] = acc[m][n][r] * inv;
        }
}

// ===========================================================================
extern "C" void kernel_launch(void* const* d_in, const int* in_sizes, int n_in,
                              void* d_out, int out_size, void* d_ws, size_t ws_size,
                              hipStream_t stream) {
    const float* q1 = (const float*)d_in[0];
    const float* q2 = (const float*)d_in[1];
    const float* U  = (const float*)d_in[2];
    float* out = (float*)d_out;

    const size_t BTD = (size_t)B_DIM * TD;   // 33.55M
    const size_t DD  = (size_t)D_DIM * D_DIM;
    const size_t BTT = (size_t)B_DIM * TT;   // 16.78M

    const size_t need = (3 * BTD + DD) * 2      // q1ht,q2ht,qUh + Uht
                      + 2 * BTT * 2             // P2', P1'
                      + 4 * (size_t)PSTR * sizeof(float2);
    if (need > ws_size) return;

    f16* q1ht = (f16*)d_ws;
    f16* q2ht = q1ht + BTD;
    f16* Uht  = q2ht + BTD;
    f16* qUh  = Uht  + DD;
    f16* P2   = qUh  + BTD;
    f16* P1   = P2   + BTT;
    float2* rowP = (float2*)(P1 + BTT);   // [2][PSTR]
    float2* colP = rowP + 2 * (size_t)PSTR;

    // D1: all casts (q1->q1ht, q2->q2ht, U->Uht), high-occupancy streaming
    k_cast<<<dim3(16, 8, 129), 256, 0, stream>>>(q1, q1ht, q2, q2ht, U, Uht);
    // D2: GEMM1 alone (full machine)
    k_gemm1<<<dim3(4, 128), 512, 0, stream>>>(q1, Uht, qUh);
    // D3: att GEMM (B reg-staged from q2 f32) -> partials + P2' + P1'
    k_att3<<<dim3(2, 2, 64), 512, 0, stream>>>(qUh, q2, P2, P1, rowP, colP);
    // D4: both align GEMMs
    k_align<<<dim3(4, 2, 128), 512, 0, stream>>>(
        P2, q2ht, rowP, out + BTD, P1, q1ht, colP, out);
}

// Round 11
// 432.853 us; speedup vs baseline: 1.0211x; 1.0211x over previous
//
#include <hip/hip_runtime.h>
#include <hip/hip_bf16.h>
#include <math.h>

#define B_DIM 64
#define T_DIM 512
#define D_DIM 1024
#define TT (T_DIM * T_DIM)   // 262144
#define TD (T_DIM * D_DIM)   // 524288
#define PSTR ((long)B_DIM * T_DIM)  // 32768: stride between the 2 softmax partials

typedef _Float16 f16;
typedef f16 f16x4 __attribute__((ext_vector_type(4)));
typedef f16 f16x8 __attribute__((ext_vector_type(8)));
typedef float f32x4 __attribute__((ext_vector_type(4)));

__device__ __forceinline__ void gld_lds16(const void* g, void* l) {
    __builtin_amdgcn_global_load_lds(
        (const __attribute__((address_space(1))) void*)g,
        (__attribute__((address_space(3))) void*)l, 16, 0, 0);
}

// LDS[r][j] holds global k-chunk (j ^ ((r>>1)&3)); conflict-free ds_read_b128.
#define SWZ(r) (((r) >> 1) & 3)

// ===========================================================================
// D1: pure streaming casts, 256 thr / 9KB LDS (high occupancy)
//   z<64:  q1 tile -> q1ht (transpose only; GEMM1 reads q1 f32 directly)
//   z<128: q2 tile -> q2h (row-major) + q2ht (transposed)
//   z==128: U -> Uht (2 tiles/block)
// ===========================================================================
__global__ __launch_bounds__(256) void k_cast(const float* __restrict__ q1,
                                              f16* __restrict__ q1ht,
                                              const float* __restrict__ q2,
                                              f16* __restrict__ q2h,
                                              f16* __restrict__ q2ht,
                                              const float* __restrict__ U,
                                              f16* __restrict__ Uht) {
    __shared__ f16 tr[64][72];
    int tid = threadIdx.x;
    int z = blockIdx.z;
    if (z < 64) {
        // q1 -> q1ht only
        int b = z;
        int d0 = blockIdx.x * 64, t0 = blockIdx.y * 64;
        const float* S = q1 + ((size_t)b * T_DIM + t0) * D_DIM + d0;
        int rr = tid >> 4, cc = (tid & 15) * 4;
#pragma unroll
        for (int i = 0; i < 4; ++i) {
            int r = rr + i * 16;
            float4 v = *(const float4*)(S + (size_t)r * D_DIM + cc);
            tr[cc + 0][r] = (f16)v.x;
            tr[cc + 1][r] = (f16)v.y;
            tr[cc + 2][r] = (f16)v.z;
            tr[cc + 3][r] = (f16)v.w;
        }
        __syncthreads();
        f16* Dt = q1ht + ((size_t)b * D_DIM + d0) * T_DIM + t0;
        int r2 = tid >> 3, c8 = (tid & 7) * 8;
#pragma unroll
        for (int i = 0; i < 2; ++i) {
            int d = r2 + i * 32;
            f16x8 vv = *(const f16x8*)(&tr[d][c8]);
            *(f16x8*)(Dt + (size_t)d * T_DIM + c8) = vv;
        }
    } else if (z < 128) {
        // q2 -> q2h + q2ht
        int b = z - 64;
        int d0 = blockIdx.x * 64, t0 = blockIdx.y * 64;
        const float* S = q2 + ((size_t)b * T_DIM + t0) * D_DIM + d0;
        f16* Dr = q2h + ((size_t)b * T_DIM + t0) * D_DIM + d0;
        int rr = tid >> 4, cc = (tid & 15) * 4;
#pragma unroll
        for (int i = 0; i < 4; ++i) {
            int r = rr + i * 16;
            float4 v = *(const float4*)(S + (size_t)r * D_DIM + cc);
            f16x4 h = {(f16)v.x, (f16)v.y, (f16)v.z, (f16)v.w};
            *(f16x4*)(Dr + (size_t)r * D_DIM + cc) = h;
            tr[cc + 0][r] = h[0];
            tr[cc + 1][r] = h[1];
            tr[cc + 2][r] = h[2];
            tr[cc + 3][r] = h[3];
        }
        __syncthreads();
        f16* Dt = q2ht + ((size_t)b * D_DIM + d0) * T_DIM + t0;
        int r2 = tid >> 3, c8 = (tid & 7) * 8;
#pragma unroll
        for (int i = 0; i < 2; ++i) {
            int d = r2 + i * 32;
            f16x8 vv = *(const f16x8*)(&tr[d][c8]);
            *(f16x8*)(Dt + (size_t)d * T_DIM + c8) = vv;
        }
    } else {
        int pos = blockIdx.y * 16 + blockIdx.x;   // 0..127
        for (int u = 0; u < 2; ++u) {
            int tile = pos + u * 128;             // 0..255
            int n0 = (tile & 15) * 64, k0 = (tile >> 4) * 64;
            int rr = tid >> 4, cc = (tid & 15) * 4;
#pragma unroll
            for (int i = 0; i < 4; ++i) {
                int r = rr + i * 16;
                float4 v = *(const float4*)(U + (size_t)(k0 + r) * D_DIM + n0 + cc);
                tr[cc + 0][r] = (f16)v.x;
                tr[cc + 1][r] = (f16)v.y;
                tr[cc + 2][r] = (f16)v.z;
                tr[cc + 3][r] = (f16)v.w;
            }
            __syncthreads();
            int r2 = tid >> 3, c8 = (tid & 7) * 8;
#pragma unroll
            for (int i = 0; i < 2; ++i) {
                int n = r2 + i * 32;
                f16x8 vv = *(const f16x8*)(&tr[n][c8]);
                *(f16x8*)(Uht + (size_t)(n0 + n) * D_DIM + k0 + c8) = vv;
            }
            __syncthreads();
        }
    }
}

// ===========================================================================
// D2: GEMM1 alone: qUh = cast(q1) @ Uht^T, A reg-staged from f32.
// grid (4,128) -> 512 blocks, full machine.
// ===========================================================================
__global__ __launch_bounds__(512, 2) void k_gemm1(const float* __restrict__ q1,
                                                  const f16* __restrict__ Uht,
                                                  f16* __restrict__ qUh) {
    __shared__ __align__(16) f16 LA[2][8192];
    __shared__ __align__(16) f16 LB[2][8192];
    const int tid = threadIdx.x;
    const int lane = tid & 63, w = tid >> 6;
    int o = blockIdx.x + 4 * blockIdx.y;          // 0..511
    int fl = (o & 7) * 64 + (o >> 3);             // XCD swizzle, nwg=512
    int bx = fl & 3, by = fl >> 2;
    const float* Aq = q1 + (long)(by * 256) * D_DIM;
    const f16* Bb = Uht + (long)(bx * 256) * D_DIM;

    const int r0 = tid >> 2, j0 = tid & 3;
    const int r1 = r0 + 128;
    const long srcA0 = (long)r0 * D_DIM + j0 * 8;
    const long srcA1 = (long)r1 * D_DIM + j0 * 8;
    const int wA0 = r0 * 32 + ((j0 ^ SWZ(r0)) << 3);
    const int wA1 = r1 * 32 + ((j0 ^ SWZ(r1)) << 3);
    const long offB0 = (long)r0 * D_DIM + (j0 ^ SWZ(r0)) * 8;
    const long offB1 = (long)r1 * D_DIM + (j0 ^ SWZ(r1)) * 8;
    const int ldsOff0 = w * 512, ldsOff1 = 4096 + w * 512;
    const int g = lane >> 4;
    const int rA0 = (w & 1) * 128 + (lane & 15);
    const int rB0 = (w >> 1) * 64 + (lane & 15);

    f32x4 acc[8][4] = {};
    {
        float4 v0 = *(const float4*)(Aq + srcA0);
        float4 v1 = *(const float4*)(Aq + srcA0 + 4);
        float4 v2 = *(const float4*)(Aq + srcA1);
        float4 v3 = *(const float4*)(Aq + srcA1 + 4);
        f16x8 h0 = {(f16)v0.x, (f16)v0.y, (f16)v0.z, (f16)v0.w,
                    (f16)v1.x, (f16)v1.y, (f16)v1.z, (f16)v1.w};
        f16x8 h1 = {(f16)v2.x, (f16)v2.y, (f16)v2.z, (f16)v2.w,
                    (f16)v3.x, (f16)v3.y, (f16)v3.z, (f16)v3.w};
        *(f16x8*)(&LA[0][wA0]) = h0;
        *(f16x8*)(&LA[0][wA1]) = h1;
        gld_lds16(Bb + offB0, &LB[0][ldsOff0]);
        gld_lds16(Bb + offB1, &LB[0][ldsOff1]);
    }
    __syncthreads();

    for (int t = 0; t < 32; ++t) {
        const int cur = t & 1;
        float4 v0, v1, v2, v3;
        if (t + 1 < 32) {
            const long kc = (long)(t + 1) << 5;
            v0 = *(const float4*)(Aq + srcA0 + kc);
            v1 = *(const float4*)(Aq + srcA0 + kc + 4);
            v2 = *(const float4*)(Aq + srcA1 + kc);
            v3 = *(const float4*)(Aq + srcA1 + kc + 4);
            gld_lds16(Bb + offB0 + kc, &LB[cur ^ 1][ldsOff0]);
            gld_lds16(Bb + offB1 + kc, &LB[cur ^ 1][ldsOff1]);
        }
        f16x8 a[8], b[4];
#pragma unroll
        for (int m = 0; m < 8; ++m) {
            int r = rA0 + m * 16;
            a[m] = *(const f16x8*)(&LA[cur][r * 32 + ((g ^ SWZ(r)) << 3)]);
        }
#pragma unroll
        for (int n = 0; n < 4; ++n) {
            int r = rB0 + n * 16;
            b[n] = *(const f16x8*)(&LB[cur][r * 32 + ((g ^ SWZ(r)) << 3)]);
        }
        __builtin_amdgcn_s_setprio(1);
#pragma unroll
        for (int m = 0; m < 8; ++m)
#pragma unroll
            for (int n = 0; n < 4; ++n)
                acc[m][n] = __builtin_amdgcn_mfma_f32_16x16x32_f16(a[m], b[n], acc[m][n], 0, 0, 0);
        __builtin_amdgcn_s_setprio(0);
        if (t + 1 < 32) {
            f16x8 h0 = {(f16)v0.x, (f16)v0.y, (f16)v0.z, (f16)v0.w,
                        (f16)v1.x, (f16)v1.y, (f16)v1.z, (f16)v1.w};
            f16x8 h1 = {(f16)v2.x, (f16)v2.y, (f16)v2.z, (f16)v2.w,
                        (f16)v3.x, (f16)v3.y, (f16)v3.z, (f16)v3.w};
            *(f16x8*)(&LA[cur ^ 1][wA0]) = h0;
            *(f16x8*)(&LA[cur ^ 1][wA1]) = h1;
        }
        __syncthreads();
    }
    const int row0 = by * 256 + (w & 1) * 128 + (lane >> 4) * 4;
    const int col0 = bx * 256 + (w >> 1) * 64 + (lane & 15);
#pragma unroll
    for (int m = 0; m < 8; ++m)
#pragma unroll
        for (int r = 0; r < 4; ++r) {
            long row = row0 + m * 16 + r;
#pragma unroll
            for (int n = 0; n < 4; ++n)
                qUh[row * D_DIM + col0 + n * 16] = (f16)acc[m][n][r];
        }
}

// ===========================================================================
// D3: att GEMM (qUh @ q2h^T), both operands f16 via gld_lds (R7-proven).
// Epilogue: relu, rowP/colP partials, P2'[t][s]=exp(att-M_rowhalf),
// P1'[s][t]=exp(att-M_colhalf). att f32 never materialized.  grid (2,2,64)
// ===========================================================================
__global__ __launch_bounds__(512, 2) void k_att3(const f16* __restrict__ qUh,
                                                 const f16* __restrict__ q2h,
                                                 f16* __restrict__ P2,
                                                 f16* __restrict__ P1,
                                                 float2* __restrict__ rowP,
                                                 float2* __restrict__ colP) {
    __shared__ __align__(16) f16 LA[2][8192];
    __shared__ __align__(16) f16 LB[2][8192];
    const int tid = threadIdx.x;
    const int lane = tid & 63, w = tid >> 6;

    int o = blockIdx.x + 2 * (blockIdx.y + 2 * blockIdx.z);  // nwg=256
    int fl = (o & 7) * 32 + (o >> 3);
    const int bx = fl & 1, by = (fl >> 1) & 1, zb = fl >> 2;

    const f16* Ab = qUh + (long)(zb * 512 + by * 256) * D_DIM;
    const f16* Bb = q2h + (long)zb * TD + (long)(bx * 256) * D_DIM;

    const int r0 = tid >> 2, j0 = tid & 3;
    const int r1 = r0 + 128;
    const long offA0 = (long)r0 * D_DIM + (j0 ^ SWZ(r0)) * 8;
    const long offA1 = (long)r1 * D_DIM + (j0 ^ SWZ(r1)) * 8;
    const int ldsOff0 = w * 512, ldsOff1 = 4096 + w * 512;
    const int g = lane >> 4;
    const int rA0 = (w & 1) * 128 + (lane & 15);
    const int rB0 = (w >> 1) * 64 + (lane & 15);

    f32x4 acc[8][4] = {};

    gld_lds16(Ab + offA0, &LA[0][ldsOff0]);
    gld_lds16(Ab + offA1, &LA[0][ldsOff1]);
    gld_lds16(Bb + offA0, &LB[0][ldsOff0]);
    gld_lds16(Bb + offA1, &LB[0][ldsOff1]);
    __syncthreads();

    for (int t = 0; t < 32; ++t) {
        const int cur = t & 1;
        if (t + 1 < 32) {
            const long kt = (long)(t + 1) << 5;
            gld_lds16(Ab + offA0 + kt, &LA[cur ^ 1][ldsOff0]);
            gld_lds16(Ab + offA1 + kt, &LA[cur ^ 1][ldsOff1]);
            gld_lds16(Bb + offA0 + kt, &LB[cur ^ 1][ldsOff0]);
            gld_lds16(Bb + offA1 + kt, &LB[cur ^ 1][ldsOff1]);
        }
        f16x8 a[8], b[4];
#pragma unroll
        for (int m = 0; m < 8; ++m) {
            int r = rA0 + m * 16;
            a[m] = *(const f16x8*)(&LA[cur][r * 32 + ((g ^ SWZ(r)) << 3)]);
        }
#pragma unroll
        for (int n = 0; n < 4; ++n) {
            int r = rB0 + n * 16;
            b[n] = *(const f16x8*)(&LB[cur][r * 32 + ((g ^ SWZ(r)) << 3)]);
        }
        __builtin_amdgcn_s_setprio(1);
#pragma unroll
        for (int m = 0; m < 8; ++m)
#pragma unroll
            for (int n = 0; n < 4; ++n)
                acc[m][n] = __builtin_amdgcn_mfma_f32_16x16x32_f16(a[m], b[n], acc[m][n], 0, 0, 0);
        __builtin_amdgcn_s_setprio(0);
        __syncthreads();
    }

    // relu
#pragma unroll
    for (int m = 0; m < 8; ++m)
#pragma unroll
        for (int n = 0; n < 4; ++n)
#pragma unroll
            for (int r = 0; r < 4; ++r)
                acc[m][n][r] = fmaxf(acc[m][n][r], 0.0f);

    // ---- softmax partials (LA reused as scratch) ----
    float* redR = (float*)(&LA[0][0]);   // [256][4][2]
    float* redC = redR + 2048;           // [2][256][2]
    float* rowM = redC + 1024;           // [256]
    float* colM = rowM + 256;            // [256]
    const int h = w & 1, cw = w >> 1;
#pragma unroll
    for (int m = 0; m < 8; ++m)
#pragma unroll
        for (int r = 0; r < 4; ++r) {
            float mx = fmaxf(fmaxf(acc[m][0][r], acc[m][1][r]),
                             fmaxf(acc[m][2][r], acc[m][3][r]));
            mx = fmaxf(mx, __shfl_xor(mx, 1));
            mx = fmaxf(mx, __shfl_xor(mx, 2));
            mx = fmaxf(mx, __shfl_xor(mx, 4));
            mx = fmaxf(mx, __shfl_xor(mx, 8));
            float sm = __expf(acc[m][0][r] - mx) + __expf(acc[m][1][r] - mx)
                     + __expf(acc[m][2][r] - mx) + __expf(acc[m][3][r] - mx);
            sm += __shfl_xor(sm, 1);
            sm += __shfl_xor(sm, 2);
            sm += __shfl_xor(sm, 4);
            sm += __shfl_xor(sm, 8);
            if ((lane & 15) == 0) {
                int lr = m * 16 + (lane >> 4) * 4 + r;
                redR[((h * 128 + lr) * 4 + cw) * 2 + 0] = mx;
                redR[((h * 128 + lr) * 4 + cw) * 2 + 1] = sm;
            }
        }
#pragma unroll
    for (int n = 0; n < 4; ++n) {
        float mx = acc[0][n][0];
#pragma unroll
        for (int m = 0; m < 8; ++m)
#pragma unroll
            for (int r = 0; r < 4; ++r) mx = fmaxf(mx, acc[m][n][r]);
        mx = fmaxf(mx, __shfl_xor(mx, 16));
        mx = fmaxf(mx, __shfl_xor(mx, 32));
        float sm = 0.f;
#pragma unroll
        for (int m = 0; m < 8; ++m)
#pragma unroll
            for (int r = 0; r < 4; ++r) sm += __expf(acc[m][n][r] - mx);
        sm += __shfl_xor(sm, 16);
        sm += __shfl_xor(sm, 32);
        if (lane < 16) {
            int c = cw * 64 + n * 16 + lane;
            redC[(h * 256 + c) * 2 + 0] = mx;
            redC[(h * 256 + c) * 2 + 1] = sm;
        }
    }
    __syncthreads();
    if (tid < 256) {
        float M = -1e30f, S = 0.f;
#pragma unroll
        for (int i = 0; i < 4; ++i) {
            float m_ = redR[(tid * 4 + i) * 2 + 0];
            float s_ = redR[(tid * 4 + i) * 2 + 1];
            float nm = fmaxf(M, m_);
            S = S * __expf(M - nm) + s_ * __expf(m_ - nm);
            M = nm;
        }
        rowP[(long)bx * PSTR + (long)zb * 512 + by * 256 + tid] = make_float2(M, S);
        rowM[tid] = M;
    } else {
        int c = tid - 256;
        float m0_ = redC[c * 2 + 0], s0_ = redC[c * 2 + 1];
        float m1_ = redC[(256 + c) * 2 + 0], s1_ = redC[(256 + c) * 2 + 1];
        float M = fmaxf(m0_, m1_);
        float S = s0_ * __expf(m0_ - M) + s1_ * __expf(m1_ - M);
        colP[(long)by * PSTR + (long)zb * 512 + bx * 256 + c] = make_float2(M, S);
        colM[c] = M;
    }
    __syncthreads();

    // ---- P2'[t][s] = f16(exp(att - M_rowhalf)) ----
    f16* P2b = P2 + (long)zb * TT;
#pragma unroll
    for (int m = 0; m < 8; ++m)
#pragma unroll
        for (int r = 0; r < 4; ++r) {
            int Lr = h * 128 + m * 16 + (lane >> 4) * 4 + r;
            float M = rowM[Lr];
            long base = (long)(by * 256 + Lr) * T_DIM + bx * 256;
#pragma unroll
            for (int n = 0; n < 4; ++n) {
                int c = cw * 64 + n * 16 + (lane & 15);
                P2b[base + c] = (f16)__expf(acc[m][n][r] - M);
            }
        }
    // ---- P1'[s][t] = f16(exp(att - M_colhalf)), 8B column stores ----
    f16* P1b = P1 + (long)zb * TT;
#pragma unroll
    for (int m = 0; m < 8; ++m) {
        int Lt = h * 128 + m * 16 + (lane >> 4) * 4;
#pragma unroll
        for (int n = 0; n < 4; ++n) {
            int Lc = cw * 64 + n * 16 + (lane & 15);
            float M = colM[Lc];
            f16x4 v = {(f16)__expf(acc[m][n][0] - M), (f16)__expf(acc[m][n][1] - M),
                       (f16)__expf(acc[m][n][2] - M), (f16)__expf(acc[m][n][3] - M)};
            *(f16x4*)(&P1b[(long)(bx * 256 + Lc) * T_DIM + by * 256 + Lt]) = v;
        }
    }
}

// ===========================================================================
// D4: both align GEMMs in one dispatch. z<64: q2align (P2', q2ht, rowP);
// z>=64: q1align (P1', q1ht, colP). A reg-staged f16 with rescale factor
// exp(M_half - M_global) per (row, k-half); epilogue * 1/S.
// grid (4,2,128)
// ===========================================================================
__global__ __launch_bounds__(512, 2) void k_align(
        const f16* __restrict__ P2, const f16* __restrict__ q2ht,
        const float2* __restrict__ rowP, float* __restrict__ outQ2,
        const f16* __restrict__ P1, const f16* __restrict__ q1ht,
        const float2* __restrict__ colP, float* __restrict__ outQ1) {
    __shared__ __align__(16) f16 LA[2][8192];
    __shared__ __align__(16) f16 LB[2][8192];
    const int tid = threadIdx.x;
    const int lane = tid & 63, w = tid >> 6;

    int o = blockIdx.x + 4 * (blockIdx.y + 2 * blockIdx.z);  // nwg=1024
    int fl = (o & 7) * 128 + (o >> 3);
    const int bx = fl & 3, by = (fl >> 2) & 1, z = fl >> 3;
    const int zb = z & 63;

    const f16* P  = (z < 64) ? P2 : P1;
    const f16* Bt = (z < 64) ? q2ht : q1ht;
    const float2* sp = ((z < 64) ? rowP : colP) + (long)zb * 512;
    float* out = ((z < 64) ? outQ2 : outQ1) + (long)zb * TD;

    const f16* Ab = P + (long)zb * TT + (long)(by * 256) * T_DIM;
    const f16* Bb = Bt + (long)zb * TD + (long)(bx * 256) * T_DIM;

    const int r0 = tid >> 2, j0 = tid & 3;
    const int r1 = r0 + 128;
    // rescale factors: fac(r, k-half) = exp(M_half - M_global)
    float2 pa0 = sp[by * 256 + r0], pb0 = sp[PSTR + by * 256 + r0];
    float M0 = fmaxf(pa0.x, pb0.x);
    f16 f00 = (f16)__expf(pa0.x - M0), f01 = (f16)__expf(pb0.x - M0);
    float2 pa1 = sp[by * 256 + r1], pb1 = sp[PSTR + by * 256 + r1];
    float M1 = fmaxf(pa1.x, pb1.x);
    f16 f10 = (f16)__expf(pa1.x - M1), f11 = (f16)__expf(pb1.x - M1);

    const long srcA0 = (long)r0 * T_DIM + j0 * 8;
    const long srcA1 = (long)r1 * T_DIM + j0 * 8;
    const int wA0 = r0 * 32 + ((j0 ^ SWZ(r0)) << 3);
    const int wA1 = r1 * 32 + ((j0 ^ SWZ(r1)) << 3);
    const long offB0 = (long)r0 * T_DIM + (j0 ^ SWZ(r0)) * 8;
    const long offB1 = (long)r1 * T_DIM + (j0 ^ SWZ(r1)) * 8;
    const int ldsOff0 = w * 512, ldsOff1 = 4096 + w * 512;
    const int g = lane >> 4;
    const int rA0 = (w & 1) * 128 + (lane & 15);
    const int rB0 = (w >> 1) * 64 + (lane & 15);

    f32x4 acc[8][4] = {};
    {
        f16x8 a0 = *(const f16x8*)(Ab + srcA0);
        f16x8 a1 = *(const f16x8*)(Ab + srcA1);
#pragma unroll
        for (int i = 0; i < 8; ++i) { a0[i] *= f00; a1[i] *= f10; }
        *(f16x8*)(&LA[0][wA0]) = a0;
        *(f16x8*)(&LA[0][wA1]) = a1;
        gld_lds16(Bb + offB0, &LB[0][ldsOff0]);
        gld_lds16(Bb + offB1, &LB[0][ldsOff1]);
    }
    __syncthreads();

    for (int t = 0; t < 16; ++t) {
        const int cur = t & 1;
        f16x8 a0n, a1n;
        if (t + 1 < 16) {
            const long kc = (long)(t + 1) << 5;
            a0n = *(const f16x8*)(Ab + srcA0 + kc);
            a1n = *(const f16x8*)(Ab + srcA1 + kc);
            gld_lds16(Bb + offB0 + kc, &LB[cur ^ 1][ldsOff0]);
            gld_lds16(Bb + offB1 + kc, &LB[cur ^ 1][ldsOff1]);
        }
        f16x8 a[8], b[4];
#pragma unroll
        for (int m = 0; m < 8; ++m) {
            int r = rA0 + m * 16;
            a[m] = *(const f16x8*)(&LA[cur][r * 32 + ((g ^ SWZ(r)) << 3)]);
        }
#pragma unroll
        for (int n = 0; n < 4; ++n) {
            int r = rB0 + n * 16;
            b[n] = *(const f16x8*)(&LB[cur][r * 32 + ((g ^ SWZ(r)) << 3)]);
        }
        __builtin_amdgcn_s_setprio(1);
#pragma unroll
        for (int m = 0; m < 8; ++m)
#pragma unroll
            for (int n = 0; n < 4; ++n)
                acc[m][n] = __builtin_amdgcn_mfma_f32_16x16x32_f16(a[m], b[n], acc[m][n], 0, 0, 0);
        __builtin_amdgcn_s_setprio(0);
        if (t + 1 < 16) {
            f16 fa = ((t + 1) & 8) ? f01 : f00;
            f16 fb = ((t + 1) & 8) ? f11 : f10;
#pragma unroll
            for (int i = 0; i < 8; ++i) { a0n[i] *= fa; a1n[i] *= fb; }
            *(f16x8*)(&LA[cur ^ 1][wA0]) = a0n;
            *(f16x8*)(&LA[cur ^ 1][wA1]) = a1n;
        }
        __syncthreads();
    }

    const int row0 = by * 256 + (w & 1) * 128 + (lane >> 4) * 4;
    const int col0 = bx * 256 + (w >> 1) * 64 + (lane & 15);
#pragma unroll
    for (int m = 0; m < 8; ++m)
#pragma unroll
        for (int r = 0; r < 4; ++r) {
            int row = row0 + m * 16 + r;
            float2 pa = sp[row], pb = sp[PSTR + row];
            float M = fmaxf(pa.x, pb.x);
            float S = pa.y * __expf(pa.x - M) + pb.y * __expf(pb.x - M);
            float inv = 1.0f / S;
#pragma unroll
            for (int n = 0; n < 4; ++n)
                out[(long)row * D_DIM + col0 + n * 16] = acc[m][n][r] * inv;
        }
}

// ===========================================================================
extern "C" void kernel_launch(void* const* d_in, const int* in_sizes, int n_in,
                              void* d_out, int out_size, void* d_ws, size_t ws_size,
                              hipStream_t stream) {
    const float* q1 = (const float*)d_in[0];
    const float* q2 = (const float*)d_in[1];
    const float* U  = (const float*)d_in[2];
    float* out = (float*)d_out;

    const size_t BTD = (size_t)B_DIM * TD;   // 33.55M
    const size_t DD  = (size_t)D_DIM * D_DIM;
    const size_t BTT = (size_t)B_DIM * TT;   // 16.78M

    const size_t need = (4 * BTD + DD) * 2      // q1ht,q2h,q2ht,qUh + Uht
                      + 2 * BTT * 2             // P2', P1'
                      + 4 * (size_t)PSTR * sizeof(float2);
    if (need > ws_size) return;

    f16* q1ht = (f16*)d_ws;
    f16* q2h  = q1ht + BTD;
    f16* q2ht = q2h  + BTD;
    f16* Uht  = q2ht + BTD;
    f16* qUh  = Uht  + DD;
    f16* P2   = qUh  + BTD;
    f16* P1   = P2   + BTT;
    float2* rowP = (float2*)(P1 + BTT);   // [2][PSTR]
    float2* colP = rowP + 2 * (size_t)PSTR;

    // D1: all casts (q1->q1ht, q2->q2h+q2ht, U->Uht), 256-thr streaming
    k_cast<<<dim3(16, 8, 129), 256, 0, stream>>>(q1, q1ht, q2, q2h, q2ht, U, Uht);
    // D2: GEMM1 alone (full machine)
    k_gemm1<<<dim3(4, 128), 512, 0, stream>>>(q1, Uht, qUh);
    // D3: att GEMM (f16 operands, gld_lds) -> partials + P2' + P1'
    k_att3<<<dim3(2, 2, 64), 512, 0, stream>>>(qUh, q2h, P2, P1, rowP, colP);
    // D4: both align GEMMs
    k_align<<<dim3(4, 2, 128), 512, 0, stream>>>(
        P2, q2ht, rowP, out + BTD, P1, q1ht, colP, out);
}

// Round 12
// 410.997 us; speedup vs baseline: 1.0754x; 1.0532x over previous
//
#include <hip/hip_runtime.h>
#include <hip/hip_bf16.h>
#include <math.h>

#define B_DIM 64
#define T_DIM 512
#define D_DIM 1024
#define TT (T_DIM * T_DIM)   // 262144
#define TD (T_DIM * D_DIM)   // 524288
#define PSTR ((long)B_DIM * T_DIM)  // 32768: stride between the 2 softmax partials

typedef _Float16 f16;
typedef f16 f16x4 __attribute__((ext_vector_type(4)));
typedef f16 f16x8 __attribute__((ext_vector_type(8)));
typedef float f32x4 __attribute__((ext_vector_type(4)));

__device__ __forceinline__ void gld_lds16(const void* g, void* l) {
    __builtin_amdgcn_global_load_lds(
        (const __attribute__((address_space(1))) void*)g,
        (__attribute__((address_space(3))) void*)l, 16, 0, 0);
}

// LDS[r][j] holds global k-chunk (j ^ ((r>>1)&3)); conflict-free ds_read_b128.
#define SWZ(r) (((r) >> 1) & 3)

// ===========================================================================
// D1: U [K][N] f32 -> Uht f16 [N][K]   (tiny: 4MB read)
// ===========================================================================
__global__ __launch_bounds__(256) void k_dU(const float* __restrict__ U,
                                            f16* __restrict__ Uht) {
    __shared__ f16 tr[64][72];
    int n0 = blockIdx.x * 64, k0 = blockIdx.y * 64;
    int tid = threadIdx.x;
    int rr = tid >> 4, cc = (tid & 15) * 4;
#pragma unroll
    for (int i = 0; i < 4; ++i) {
        int r = rr + i * 16;
        float4 v = *(const float4*)(U + (size_t)(k0 + r) * D_DIM + n0 + cc);
        tr[cc + 0][r] = (f16)v.x;
        tr[cc + 1][r] = (f16)v.y;
        tr[cc + 2][r] = (f16)v.z;
        tr[cc + 3][r] = (f16)v.w;
    }
    __syncthreads();
    int r2 = tid >> 3, c8 = (tid & 7) * 8;
#pragma unroll
    for (int i = 0; i < 2; ++i) {
        int n = r2 + i * 32;
        f16x8 vv = *(const f16x8*)(&tr[n][c8]);
        *(f16x8*)(Uht + (size_t)(n0 + n) * D_DIM + k0 + c8) = vv;
    }
}

// ===========================================================================
// D2 (R7-proven): GEMM1 (qUh = cast(q1) @ Uht^T, A reg-staged from f32)
//     || cast q2 -> q2h,q2ht
// grid (4, 128 + 1024): by<128 GEMM; else q2 cast (2 tiles/block)
// ===========================================================================
__global__ __launch_bounds__(512, 2) void k_d2(const float* __restrict__ q1,
                                               const f16* __restrict__ Uht,
                                               f16* __restrict__ qUh,
                                               const float* __restrict__ q2,
                                               f16* __restrict__ q2h,
                                               f16* __restrict__ q2ht) {
    __shared__ __align__(16) f16 SM[32768];   // 64KB union
    int tid = threadIdx.x;
    if (blockIdx.y < 128) {
        // ---------------- GEMM1 ----------------
        f16 (*LA)[8192] = (f16(*)[8192])SM;
        f16 (*LB)[8192] = (f16(*)[8192])(SM + 16384);
        const int lane = tid & 63, w = tid >> 6;
        int o = blockIdx.x + 4 * blockIdx.y;          // 0..511
        int fl = (o & 7) * 64 + (o >> 3);             // XCD swizzle, nwg=512
        int bx = fl & 3, by = fl >> 2;
        const float* Aq = q1 + (long)(by * 256) * D_DIM;
        const f16* Bb = Uht + (long)(bx * 256) * D_DIM;

        const int r0 = tid >> 2, j0 = tid & 3;
        const int r1 = r0 + 128;
        const long srcA0 = (long)r0 * D_DIM + j0 * 8;
        const long srcA1 = (long)r1 * D_DIM + j0 * 8;
        const int wA0 = r0 * 32 + ((j0 ^ SWZ(r0)) << 3);
        const int wA1 = r1 * 32 + ((j0 ^ SWZ(r1)) << 3);
        const long offB0 = (long)r0 * D_DIM + (j0 ^ SWZ(r0)) * 8;
        const long offB1 = (long)r1 * D_DIM + (j0 ^ SWZ(r1)) * 8;
        const int ldsOff0 = w * 512, ldsOff1 = 4096 + w * 512;
        const int g = lane >> 4;
        const int rA0 = (w & 1) * 128 + (lane & 15);
        const int rB0 = (w >> 1) * 64 + (lane & 15);

        f32x4 acc[8][4] = {};
        {
            float4 v0 = *(const float4*)(Aq + srcA0);
            float4 v1 = *(const float4*)(Aq + srcA0 + 4);
            float4 v2 = *(const float4*)(Aq + srcA1);
            float4 v3 = *(const float4*)(Aq + srcA1 + 4);
            f16x8 h0 = {(f16)v0.x, (f16)v0.y, (f16)v0.z, (f16)v0.w,
                        (f16)v1.x, (f16)v1.y, (f16)v1.z, (f16)v1.w};
            f16x8 h1 = {(f16)v2.x, (f16)v2.y, (f16)v2.z, (f16)v2.w,
                        (f16)v3.x, (f16)v3.y, (f16)v3.z, (f16)v3.w};
            *(f16x8*)(&LA[0][wA0]) = h0;
            *(f16x8*)(&LA[0][wA1]) = h1;
            gld_lds16(Bb + offB0, &LB[0][ldsOff0]);
            gld_lds16(Bb + offB1, &LB[0][ldsOff1]);
        }
        __syncthreads();

        for (int t = 0; t < 32; ++t) {
            const int cur = t & 1;
            float4 v0, v1, v2, v3;
            if (t + 1 < 32) {
                const long kc = (long)(t + 1) << 5;
                v0 = *(const float4*)(Aq + srcA0 + kc);
                v1 = *(const float4*)(Aq + srcA0 + kc + 4);
                v2 = *(const float4*)(Aq + srcA1 + kc);
                v3 = *(const float4*)(Aq + srcA1 + kc + 4);
                gld_lds16(Bb + offB0 + kc, &LB[cur ^ 1][ldsOff0]);
                gld_lds16(Bb + offB1 + kc, &LB[cur ^ 1][ldsOff1]);
            }
            f16x8 a[8], b[4];
#pragma unroll
            for (int m = 0; m < 8; ++m) {
                int r = rA0 + m * 16;
                a[m] = *(const f16x8*)(&LA[cur][r * 32 + ((g ^ SWZ(r)) << 3)]);
            }
#pragma unroll
            for (int n = 0; n < 4; ++n) {
                int r = rB0 + n * 16;
                b[n] = *(const f16x8*)(&LB[cur][r * 32 + ((g ^ SWZ(r)) << 3)]);
            }
            __builtin_amdgcn_s_setprio(1);
#pragma unroll
            for (int m = 0; m < 8; ++m)
#pragma unroll
                for (int n = 0; n < 4; ++n)
                    acc[m][n] = __builtin_amdgcn_mfma_f32_16x16x32_f16(a[m], b[n], acc[m][n], 0, 0, 0);
            __builtin_amdgcn_s_setprio(0);
            if (t + 1 < 32) {
                f16x8 h0 = {(f16)v0.x, (f16)v0.y, (f16)v0.z, (f16)v0.w,
                            (f16)v1.x, (f16)v1.y, (f16)v1.z, (f16)v1.w};
                f16x8 h1 = {(f16)v2.x, (f16)v2.y, (f16)v2.z, (f16)v2.w,
                            (f16)v3.x, (f16)v3.y, (f16)v3.z, (f16)v3.w};
                *(f16x8*)(&LA[cur ^ 1][wA0]) = h0;
                *(f16x8*)(&LA[cur ^ 1][wA1]) = h1;
            }
            __syncthreads();
        }
        const int row0 = by * 256 + (w & 1) * 128 + (lane >> 4) * 4;
        const int col0 = bx * 256 + (w >> 1) * 64 + (lane & 15);
#pragma unroll
        for (int m = 0; m < 8; ++m)
#pragma unroll
            for (int r = 0; r < 4; ++r) {
                long row = row0 + m * 16 + r;
#pragma unroll
                for (int n = 0; n < 4; ++n)
                    qUh[row * D_DIM + col0 + n * 16] = (f16)acc[m][n][r];
            }
    } else {
        // ---------------- cast q2 (2 tiles per block) ----------------
        int hf = tid >> 8, t2 = tid & 255;
        f16 (*tr)[72] = (f16(*)[72])(SM + hf * 4608);
        int p = (blockIdx.y - 128) * 4 + blockIdx.x;  // 0..4095
        int tile = p * 2 + hf;                        // 0..8191
        int b = tile >> 7, rem = tile & 127;
        int d0 = (rem & 15) * 64, t0 = (rem >> 4) * 64;
        const float* S = q2 + ((size_t)b * T_DIM + t0) * D_DIM + d0;
        f16* Dr = q2h + ((size_t)b * T_DIM + t0) * D_DIM + d0;
        int rr = t2 >> 4, cc = (t2 & 15) * 4;
#pragma unroll
        for (int i = 0; i < 4; ++i) {
            int r = rr + i * 16;
            float4 v = *(const float4*)(S + (size_t)r * D_DIM + cc);
            f16x4 h = {(f16)v.x, (f16)v.y, (f16)v.z, (f16)v.w};
            *(f16x4*)(Dr + (size_t)r * D_DIM + cc) = h;
            tr[cc + 0][r] = h[0];
            tr[cc + 1][r] = h[1];
            tr[cc + 2][r] = h[2];
            tr[cc + 3][r] = h[3];
        }
        __syncthreads();
        f16* Dt = q2ht + ((size_t)b * D_DIM + d0) * T_DIM + t0;
        int r2 = t2 >> 3, c8 = (t2 & 7) * 8;
#pragma unroll
        for (int i = 0; i < 2; ++i) {
            int d = r2 + i * 32;
            f16x8 vv = *(const f16x8*)(&tr[d][c8]);
            *(f16x8*)(Dt + (size_t)d * T_DIM + c8) = vv;
        }
    }
}

// ===========================================================================
// D3: att GEMM (qUh @ q2h^T, f16 gld_lds both operands — R7-proven)
//     || cast q1 -> q1ht (fills D3's idle block slots; q1ht used only by D4)
// grid (4, 64 + 1024): by<64 GEMM (256 blocks); else cast (2 tiles/block)
// Epilogue: relu, rowP/colP partials, P2'[t][s]=exp(att-M_rowhalf),
// P1'[s][t]=exp(att-M_colhalf). att f32 never materialized.
// ===========================================================================
__global__ __launch_bounds__(512, 2) void k_att3(const f16* __restrict__ qUh,
                                                 const f16* __restrict__ q2h,
                                                 f16* __restrict__ P2,
                                                 f16* __restrict__ P1,
                                                 float2* __restrict__ rowP,
                                                 float2* __restrict__ colP,
                                                 const float* __restrict__ q1,
                                                 f16* __restrict__ q1ht) {
    __shared__ __align__(16) f16 LA[2][8192];
    __shared__ __align__(16) f16 LB[2][8192];
    const int tid = threadIdx.x;

    if (blockIdx.y >= 64) {
        // ---------------- cast q1 -> q1ht (2 tiles per block) ------------
        int hf = tid >> 8, t2 = tid & 255;
        f16 (*tr)[72] = (f16(*)[72])((f16*)LA + hf * 4608);
        int p = (blockIdx.y - 64) * 4 + blockIdx.x;   // 0..4095
        int tile = p * 2 + hf;                        // 0..8191
        int b = tile >> 7, rem = tile & 127;
        int d0 = (rem & 15) * 64, t0 = (rem >> 4) * 64;
        const float* S = q1 + ((size_t)b * T_DIM + t0) * D_DIM + d0;
        int rr = t2 >> 4, cc = (t2 & 15) * 4;
#pragma unroll
        for (int i = 0; i < 4; ++i) {
            int r = rr + i * 16;
            float4 v = *(const float4*)(S + (size_t)r * D_DIM + cc);
            tr[cc + 0][r] = (f16)v.x;
            tr[cc + 1][r] = (f16)v.y;
            tr[cc + 2][r] = (f16)v.z;
            tr[cc + 3][r] = (f16)v.w;
        }
        __syncthreads();
        f16* Dt = q1ht + ((size_t)b * D_DIM + d0) * T_DIM + t0;
        int r2 = t2 >> 3, c8 = (t2 & 7) * 8;
#pragma unroll
        for (int i = 0; i < 2; ++i) {
            int d = r2 + i * 32;
            f16x8 vv = *(const f16x8*)(&tr[d][c8]);
            *(f16x8*)(Dt + (size_t)d * T_DIM + c8) = vv;
        }
        return;
    }

    // ---------------- att GEMM ----------------
    const int lane = tid & 63, w = tid >> 6;
    int o = blockIdx.x + 4 * blockIdx.y;          // 0..255
    int fl = (o & 7) * 32 + (o >> 3);             // XCD swizzle, nwg=256
    const int bx = fl & 1, by = (fl >> 1) & 1, zb = fl >> 2;

    const f16* Ab = qUh + (long)(zb * 512 + by * 256) * D_DIM;
    const f16* Bb = q2h + (long)zb * TD + (long)(bx * 256) * D_DIM;

    const int r0 = tid >> 2, j0 = tid & 3;
    const int r1 = r0 + 128;
    const long offA0 = (long)r0 * D_DIM + (j0 ^ SWZ(r0)) * 8;
    const long offA1 = (long)r1 * D_DIM + (j0 ^ SWZ(r1)) * 8;
    const int ldsOff0 = w * 512, ldsOff1 = 4096 + w * 512;
    const int g = lane >> 4;
    const int rA0 = (w & 1) * 128 + (lane & 15);
    const int rB0 = (w >> 1) * 64 + (lane & 15);

    f32x4 acc[8][4] = {};

    gld_lds16(Ab + offA0, &LA[0][ldsOff0]);
    gld_lds16(Ab + offA1, &LA[0][ldsOff1]);
    gld_lds16(Bb + offA0, &LB[0][ldsOff0]);
    gld_lds16(Bb + offA1, &LB[0][ldsOff1]);
    __syncthreads();

    for (int t = 0; t < 32; ++t) {
        const int cur = t & 1;
        if (t + 1 < 32) {
            const long kt = (long)(t + 1) << 5;
            gld_lds16(Ab + offA0 + kt, &LA[cur ^ 1][ldsOff0]);
            gld_lds16(Ab + offA1 + kt, &LA[cur ^ 1][ldsOff1]);
            gld_lds16(Bb + offA0 + kt, &LB[cur ^ 1][ldsOff0]);
            gld_lds16(Bb + offA1 + kt, &LB[cur ^ 1][ldsOff1]);
        }
        f16x8 a[8], b[4];
#pragma unroll
        for (int m = 0; m < 8; ++m) {
            int r = rA0 + m * 16;
            a[m] = *(const f16x8*)(&LA[cur][r * 32 + ((g ^ SWZ(r)) << 3)]);
        }
#pragma unroll
        for (int n = 0; n < 4; ++n) {
            int r = rB0 + n * 16;
            b[n] = *(const f16x8*)(&LB[cur][r * 32 + ((g ^ SWZ(r)) << 3)]);
        }
        __builtin_amdgcn_s_setprio(1);
#pragma unroll
        for (int m = 0; m < 8; ++m)
#pragma unroll
            for (int n = 0; n < 4; ++n)
                acc[m][n] = __builtin_amdgcn_mfma_f32_16x16x32_f16(a[m], b[n], acc[m][n], 0, 0, 0);
        __builtin_amdgcn_s_setprio(0);
        __syncthreads();
    }

    // relu
#pragma unroll
    for (int m = 0; m < 8; ++m)
#pragma unroll
        for (int n = 0; n < 4; ++n)
#pragma unroll
            for (int r = 0; r < 4; ++r)
                acc[m][n][r] = fmaxf(acc[m][n][r], 0.0f);

    // ---- softmax partials (LA reused as scratch) ----
    float* redR = (float*)(&LA[0][0]);   // [256][4][2]
    float* redC = redR + 2048;           // [2][256][2]
    float* rowM = redC + 1024;           // [256]
    float* colM = rowM + 256;            // [256]
    const int h = w & 1, cw = w >> 1;
#pragma unroll
    for (int m = 0; m < 8; ++m)
#pragma unroll
        for (int r = 0; r < 4; ++r) {
            float mx = fmaxf(fmaxf(acc[m][0][r], acc[m][1][r]),
                             fmaxf(acc[m][2][r], acc[m][3][r]));
            mx = fmaxf(mx, __shfl_xor(mx, 1));
            mx = fmaxf(mx, __shfl_xor(mx, 2));
            mx = fmaxf(mx, __shfl_xor(mx, 4));
            mx = fmaxf(mx, __shfl_xor(mx, 8));
            float sm = __expf(acc[m][0][r] - mx) + __expf(acc[m][1][r] - mx)
                     + __expf(acc[m][2][r] - mx) + __expf(acc[m][3][r] - mx);
            sm += __shfl_xor(sm, 1);
            sm += __shfl_xor(sm, 2);
            sm += __shfl_xor(sm, 4);
            sm += __shfl_xor(sm, 8);
            if ((lane & 15) == 0) {
                int lr = m * 16 + (lane >> 4) * 4 + r;
                redR[((h * 128 + lr) * 4 + cw) * 2 + 0] = mx;
                redR[((h * 128 + lr) * 4 + cw) * 2 + 1] = sm;
            }
        }
#pragma unroll
    for (int n = 0; n < 4; ++n) {
        float mx = acc[0][n][0];
#pragma unroll
        for (int m = 0; m < 8; ++m)
#pragma unroll
            for (int r = 0; r < 4; ++r) mx = fmaxf(mx, acc[m][n][r]);
        mx = fmaxf(mx, __shfl_xor(mx, 16));
        mx = fmaxf(mx, __shfl_xor(mx, 32));
        float sm = 0.f;
#pragma unroll
        for (int m = 0; m < 8; ++m)
#pragma unroll
            for (int r = 0; r < 4; ++r) sm += __expf(acc[m][n][r] - mx);
        sm += __shfl_xor(sm, 16);
        sm += __shfl_xor(sm, 32);
        if (lane < 16) {
            int c = cw * 64 + n * 16 + lane;
            redC[(h * 256 + c) * 2 + 0] = mx;
            redC[(h * 256 + c) * 2 + 1] = sm;
        }
    }
    __syncthreads();
    if (tid < 256) {
        float M = -1e30f, S = 0.f;
#pragma unroll
        for (int i = 0; i < 4; ++i) {
            float m_ = redR[(tid * 4 + i) * 2 + 0];
            float s_ = redR[(tid * 4 + i) * 2 + 1];
            float nm = fmaxf(M, m_);
            S = S * __expf(M - nm) + s_ * __expf(m_ - nm);
            M = nm;
        }
        rowP[(long)bx * PSTR + (long)zb * 512 + by * 256 + tid] = make_float2(M, S);
        rowM[tid] = M;
    } else {
        int c = tid - 256;
        float m0_ = redC[c * 2 + 0], s0_ = redC[c * 2 + 1];
        float m1_ = redC[(256 + c) * 2 + 0], s1_ = redC[(256 + c) * 2 + 1];
        float M = fmaxf(m0_, m1_);
        float S = s0_ * __expf(m0_ - M) + s1_ * __expf(m1_ - M);
        colP[(long)by * PSTR + (long)zb * 512 + bx * 256 + c] = make_float2(M, S);
        colM[c] = M;
    }
    __syncthreads();

    // ---- P2'[t][s] = f16(exp(att - M_rowhalf)) ----
    f16* P2b = P2 + (long)zb * TT;
#pragma unroll
    for (int m = 0; m < 8; ++m)
#pragma unroll
        for (int r = 0; r < 4; ++r) {
            int Lr = h * 128 + m * 16 + (lane >> 4) * 4 + r;
            float M = rowM[Lr];
            long base = (long)(by * 256 + Lr) * T_DIM + bx * 256;
#pragma unroll
            for (int n = 0; n < 4; ++n) {
                int c = cw * 64 + n * 16 + (lane & 15);
                P2b[base + c] = (f16)__expf(acc[m][n][r] - M);
            }
        }
    // ---- P1'[s][t] = f16(exp(att - M_colhalf)), 8B column stores ----
    f16* P1b = P1 + (long)zb * TT;
#pragma unroll
    for (int m = 0; m < 8; ++m) {
        int Lt = h * 128 + m * 16 + (lane >> 4) * 4;
#pragma unroll
        for (int n = 0; n < 4; ++n) {
            int Lc = cw * 64 + n * 16 + (lane & 15);
            float M = colM[Lc];
            f16x4 v = {(f16)__expf(acc[m][n][0] - M), (f16)__expf(acc[m][n][1] - M),
                       (f16)__expf(acc[m][n][2] - M), (f16)__expf(acc[m][n][3] - M)};
            *(f16x4*)(&P1b[(long)(bx * 256 + Lc) * T_DIM + by * 256 + Lt]) = v;
        }
    }
}

// ===========================================================================
// D4: both align GEMMs in one dispatch. z<64: q2align (P2', q2ht, rowP);
// z>=64: q1align (P1', q1ht, colP). A reg-staged f16 with rescale factor
// exp(M_half - M_global) per (row, k-half); epilogue * 1/S.
// grid (4,2,128)
// ===========================================================================
__global__ __launch_bounds__(512, 2) void k_align(
        const f16* __restrict__ P2, const f16* __restrict__ q2ht,
        const float2* __restrict__ rowP, float* __restrict__ outQ2,
        const f16* __restrict__ P1, const f16* __restrict__ q1ht,
        const float2* __restrict__ colP, float* __restrict__ outQ1) {
    __shared__ __align__(16) f16 LA[2][8192];
    __shared__ __align__(16) f16 LB[2][8192];
    const int tid = threadIdx.x;
    const int lane = tid & 63, w = tid >> 6;

    int o = blockIdx.x + 4 * (blockIdx.y + 2 * blockIdx.z);  // nwg=1024
    int fl = (o & 7) * 128 + (o >> 3);
    const int bx = fl & 3, by = (fl >> 2) & 1, z = fl >> 3;
    const int zb = z & 63;

    const f16* P  = (z < 64) ? P2 : P1;
    const f16* Bt = (z < 64) ? q2ht : q1ht;
    const float2* sp = ((z < 64) ? rowP : colP) + (long)zb * 512;
    float* out = ((z < 64) ? outQ2 : outQ1) + (long)zb * TD;

    const f16* Ab = P + (long)zb * TT + (long)(by * 256) * T_DIM;
    const f16* Bb = Bt + (long)zb * TD + (long)(bx * 256) * T_DIM;

    const int r0 = tid >> 2, j0 = tid & 3;
    const int r1 = r0 + 128;
    // rescale factors: fac(r, k-half) = exp(M_half - M_global)
    float2 pa0 = sp[by * 256 + r0], pb0 = sp[PSTR + by * 256 + r0];
    float M0 = fmaxf(pa0.x, pb0.x);
    f16 f00 = (f16)__expf(pa0.x - M0), f01 = (f16)__expf(pb0.x - M0);
    float2 pa1 = sp[by * 256 + r1], pb1 = sp[PSTR + by * 256 + r1];
    float M1 = fmaxf(pa1.x, pb1.x);
    f16 f10 = (f16)__expf(pa1.x - M1), f11 = (f16)__expf(pb1.x - M1);

    const long srcA0 = (long)r0 * T_DIM + j0 * 8;
    const long srcA1 = (long)r1 * T_DIM + j0 * 8;
    const int wA0 = r0 * 32 + ((j0 ^ SWZ(r0)) << 3);
    const int wA1 = r1 * 32 + ((j0 ^ SWZ(r1)) << 3);
    const long offB0 = (long)r0 * T_DIM + (j0 ^ SWZ(r0)) * 8;
    const long offB1 = (long)r1 * T_DIM + (j0 ^ SWZ(r1)) * 8;
    const int ldsOff0 = w * 512, ldsOff1 = 4096 + w * 512;
    const int g = lane >> 4;
    const int rA0 = (w & 1) * 128 + (lane & 15);
    const int rB0 = (w >> 1) * 64 + (lane & 15);

    f32x4 acc[8][4] = {};
    {
        f16x8 a0 = *(const f16x8*)(Ab + srcA0);
        f16x8 a1 = *(const f16x8*)(Ab + srcA1);
#pragma unroll
        for (int i = 0; i < 8; ++i) { a0[i] *= f00; a1[i] *= f10; }
        *(f16x8*)(&LA[0][wA0]) = a0;
        *(f16x8*)(&LA[0][wA1]) = a1;
        gld_lds16(Bb + offB0, &LB[0][ldsOff0]);
        gld_lds16(Bb + offB1, &LB[0][ldsOff1]);
    }
    __syncthreads();

    for (int t = 0; t < 16; ++t) {
        const int cur = t & 1;
        f16x8 a0n, a1n;
        if (t + 1 < 16) {
            const long kc = (long)(t + 1) << 5;
            a0n = *(const f16x8*)(Ab + srcA0 + kc);
            a1n = *(const f16x8*)(Ab + srcA1 + kc);
            gld_lds16(Bb + offB0 + kc, &LB[cur ^ 1][ldsOff0]);
            gld_lds16(Bb + offB1 + kc, &LB[cur ^ 1][ldsOff1]);
        }
        f16x8 a[8], b[4];
#pragma unroll
        for (int m = 0; m < 8; ++m) {
            int r = rA0 + m * 16;
            a[m] = *(const f16x8*)(&LA[cur][r * 32 + ((g ^ SWZ(r)) << 3)]);
        }
#pragma unroll
        for (int n = 0; n < 4; ++n) {
            int r = rB0 + n * 16;
            b[n] = *(const f16x8*)(&LB[cur][r * 32 + ((g ^ SWZ(r)) << 3)]);
        }
        __builtin_amdgcn_s_setprio(1);
#pragma unroll
        for (int m = 0; m < 8; ++m)
#pragma unroll
            for (int n = 0; n < 4; ++n)
                acc[m][n] = __builtin_amdgcn_mfma_f32_16x16x32_f16(a[m], b[n], acc[m][n], 0, 0, 0);
        __builtin_amdgcn_s_setprio(0);
        if (t + 1 < 16) {
            f16 fa = ((t + 1) & 8) ? f01 : f00;
            f16 fb = ((t + 1) & 8) ? f11 : f10;
#pragma unroll
            for (int i = 0; i < 8; ++i) { a0n[i] *= fa; a1n[i] *= fb; }
            *(f16x8*)(&LA[cur ^ 1][wA0]) = a0n;
            *(f16x8*)(&LA[cur ^ 1][wA1]) = a1n;
        }
        __syncthreads();
    }

    const int row0 = by * 256 + (w & 1) * 128 + (lane >> 4) * 4;
    const int col0 = bx * 256 + (w >> 1) * 64 + (lane & 15);
#pragma unroll
    for (int m = 0; m < 8; ++m)
#pragma unroll
        for (int r = 0; r < 4; ++r) {
            int row = row0 + m * 16 + r;
            float2 pa = sp[row], pb = sp[PSTR + row];
            float M = fmaxf(pa.x, pb.x);
            float S = pa.y * __expf(pa.x - M) + pb.y * __expf(pb.x - M);
            float inv = 1.0f / S;
#pragma unroll
            for (int n = 0; n < 4; ++n)
                out[(long)row * D_DIM + col0 + n * 16] = acc[m][n][r] * inv;
        }
}

// ===========================================================================
extern "C" void kernel_launch(void* const* d_in, const int* in_sizes, int n_in,
                              void* d_out, int out_size, void* d_ws, size_t ws_size,
                              hipStream_t stream) {
    const float* q1 = (const float*)d_in[0];
    const float* q2 = (const float*)d_in[1];
    const float* U  = (const float*)d_in[2];
    float* out = (float*)d_out;

    const size_t BTD = (size_t)B_DIM * TD;   // 33.55M
    const size_t DD  = (size_t)D_DIM * D_DIM;
    const size_t BTT = (size_t)B_DIM * TT;   // 16.78M

    const size_t need = (4 * BTD + DD) * 2      // q1ht,q2h,q2ht,qUh + Uht
                      + 2 * BTT * 2             // P2', P1'
                      + 4 * (size_t)PSTR * sizeof(float2);
    if (need > ws_size) return;

    f16* q1ht = (f16*)d_ws;
    f16* q2h  = q1ht + BTD;
    f16* q2ht = q2h  + BTD;
    f16* Uht  = q2ht + BTD;
    f16* qUh  = Uht  + DD;
    f16* P2   = qUh  + BTD;
    f16* P1   = P2   + BTT;
    float2* rowP = (float2*)(P1 + BTT);   // [2][PSTR]
    float2* colP = rowP + 2 * (size_t)PSTR;

    // D1: U -> Uht (tiny)
    k_dU<<<dim3(16, 16), 256, 0, stream>>>(U, Uht);
    // D2: GEMM1 (A from q1 f32) || cast q2 -> q2h,q2ht  (R7-proven)
    k_d2<<<dim3(4, 128 + 1024), 512, 0, stream>>>(q1, Uht, qUh, q2, q2h, q2ht);
    // D3: att GEMM || cast q1 -> q1ht (fills idle slots; q1ht used by D4 only)
    k_att3<<<dim3(4, 64 + 1024), 512, 0, stream>>>(
        qUh, q2h, P2, P1, rowP, colP, q1, q1ht);
    // D4: both align GEMMs
    k_align<<<dim3(4, 2, 128), 512, 0, stream>>>(
        P2, q2ht, rowP, out + BTD, P1, q1ht, colP, out);
}

// Round 13
// 388.158 us; speedup vs baseline: 1.1387x; 1.0588x over previous
//
#include <hip/hip_runtime.h>
#include <hip/hip_bf16.h>
#include <math.h>

#define B_DIM 64
#define T_DIM 512
#define D_DIM 1024
#define TT (T_DIM * T_DIM)   // 262144
#define TD (T_DIM * D_DIM)   // 524288
#define PSTR ((long)B_DIM * T_DIM)  // 32768: stride between the 2 softmax partials

typedef _Float16 f16;
typedef f16 f16x4 __attribute__((ext_vector_type(4)));
typedef f16 f16x8 __attribute__((ext_vector_type(8)));
typedef float f32x4 __attribute__((ext_vector_type(4)));

__device__ __forceinline__ void gld_lds16(const void* g, void* l) {
    __builtin_amdgcn_global_load_lds(
        (const __attribute__((address_space(1))) void*)g,
        (__attribute__((address_space(3))) void*)l, 16, 0, 0);
}

// LDS[r][j] holds global k-chunk (j ^ ((r>>1)&3)); conflict-free ds_read_b128.
#define SWZ(r) (((r) >> 1) & 3)

// ===========================================================================
// D1 (R7-proven): cast q1 -> q1ht, and U -> Uht. 256 thr / 9KB LDS.
// ===========================================================================
__global__ __launch_bounds__(256) void k_d1(const float* __restrict__ q1,
                                            f16* __restrict__ q1ht,
                                            const float* __restrict__ U,
                                            f16* __restrict__ Uht) {
    __shared__ f16 tr[64][72];
    int tid = threadIdx.x;
    int z = blockIdx.z;
    if (z < 64) {
        int b = z;
        int d0 = blockIdx.x * 64, t0 = blockIdx.y * 64;
        const float* S = q1 + ((size_t)b * T_DIM + t0) * D_DIM + d0;
        int rr = tid >> 4, cc = (tid & 15) * 4;
#pragma unroll
        for (int i = 0; i < 4; ++i) {
            int r = rr + i * 16;
            float4 v = *(const float4*)(S + (size_t)r * D_DIM + cc);
            tr[cc + 0][r] = (f16)v.x;
            tr[cc + 1][r] = (f16)v.y;
            tr[cc + 2][r] = (f16)v.z;
            tr[cc + 3][r] = (f16)v.w;
        }
        __syncthreads();
        f16* Dt = q1ht + ((size_t)b * D_DIM + d0) * T_DIM + t0;
        int r2 = tid >> 3, c8 = (tid & 7) * 8;
#pragma unroll
        for (int i = 0; i < 2; ++i) {
            int d = r2 + i * 32;
            f16x8 vv = *(const f16x8*)(&tr[d][c8]);
            *(f16x8*)(Dt + (size_t)d * T_DIM + c8) = vv;
        }
    } else {
        int pos = blockIdx.y * 16 + blockIdx.x;   // 0..127
        for (int u = 0; u < 2; ++u) {
            int tile = pos + u * 128;             // 0..255
            int n0 = (tile & 15) * 64, k0 = (tile >> 4) * 64;
            int rr = tid >> 4, cc = (tid & 15) * 4;
#pragma unroll
            for (int i = 0; i < 4; ++i) {
                int r = rr + i * 16;
                float4 v = *(const float4*)(U + (size_t)(k0 + r) * D_DIM + n0 + cc);
                tr[cc + 0][r] = (f16)v.x;
                tr[cc + 1][r] = (f16)v.y;
                tr[cc + 2][r] = (f16)v.z;
                tr[cc + 3][r] = (f16)v.w;
            }
            __syncthreads();
            int r2 = tid >> 3, c8 = (tid & 7) * 8;
#pragma unroll
            for (int i = 0; i < 2; ++i) {
                int n = r2 + i * 32;
                f16x8 vv = *(const f16x8*)(&tr[n][c8]);
                *(f16x8*)(Uht + (size_t)(n0 + n) * D_DIM + k0 + c8) = vv;
            }
            __syncthreads();
        }
    }
}

// ===========================================================================
// D2: GEMM1 (qUh = cast(q1) @ Uht^T, A reg-staged from f32, 2-DEEP prefetch)
//     || cast q2 -> q2h,q2ht
// grid (4, 128 + 1024)
// ===========================================================================
__global__ __launch_bounds__(512, 2) void k_d2(const float* __restrict__ q1,
                                               const f16* __restrict__ Uht,
                                               f16* __restrict__ qUh,
                                               const float* __restrict__ q2,
                                               f16* __restrict__ q2h,
                                               f16* __restrict__ q2ht) {
    __shared__ __align__(16) f16 SM[32768];   // 64KB union
    int tid = threadIdx.x;
    if (blockIdx.y < 128) {
        // ---------------- GEMM1 ----------------
        f16 (*LA)[8192] = (f16(*)[8192])SM;
        f16 (*LB)[8192] = (f16(*)[8192])(SM + 16384);
        const int lane = tid & 63, w = tid >> 6;
        int o = blockIdx.x + 4 * blockIdx.y;          // 0..511
        int fl = (o & 7) * 64 + (o >> 3);             // XCD swizzle, nwg=512
        int bx = fl & 3, by = fl >> 2;
        const float* Aq = q1 + (long)(by * 256) * D_DIM;
        const f16* Bb = Uht + (long)(bx * 256) * D_DIM;

        const int r0 = tid >> 2, j0 = tid & 3;
        const int r1 = r0 + 128;
        const long srcA0 = (long)r0 * D_DIM + j0 * 8;
        const long srcA1 = (long)r1 * D_DIM + j0 * 8;
        const int wA0 = r0 * 32 + ((j0 ^ SWZ(r0)) << 3);
        const int wA1 = r1 * 32 + ((j0 ^ SWZ(r1)) << 3);
        const long offB0 = (long)r0 * D_DIM + (j0 ^ SWZ(r0)) * 8;
        const long offB1 = (long)r1 * D_DIM + (j0 ^ SWZ(r1)) * 8;
        const int ldsOff0 = w * 512, ldsOff1 = 4096 + w * 512;
        const int g = lane >> 4;
        const int rA0 = (w & 1) * 128 + (lane & 15);
        const int rB0 = (w >> 1) * 64 + (lane & 15);

        f32x4 acc[8][4] = {};
        // pending A(t+1) registers
        float4 p0, p1, p2, p3;
        {
            // A(0): synchronous load+cvt+write
            float4 v0 = *(const float4*)(Aq + srcA0);
            float4 v1 = *(const float4*)(Aq + srcA0 + 4);
            float4 v2 = *(const float4*)(Aq + srcA1);
            float4 v3 = *(const float4*)(Aq + srcA1 + 4);
            f16x8 h0 = {(f16)v0.x, (f16)v0.y, (f16)v0.z, (f16)v0.w,
                        (f16)v1.x, (f16)v1.y, (f16)v1.z, (f16)v1.w};
            f16x8 h1 = {(f16)v2.x, (f16)v2.y, (f16)v2.z, (f16)v2.w,
                        (f16)v3.x, (f16)v3.y, (f16)v3.z, (f16)v3.w};
            *(f16x8*)(&LA[0][wA0]) = h0;
            *(f16x8*)(&LA[0][wA1]) = h1;
            // A(1) pending
            p0 = *(const float4*)(Aq + srcA0 + 32);
            p1 = *(const float4*)(Aq + srcA0 + 36);
            p2 = *(const float4*)(Aq + srcA1 + 32);
            p3 = *(const float4*)(Aq + srcA1 + 36);
            gld_lds16(Bb + offB0, &LB[0][ldsOff0]);
            gld_lds16(Bb + offB1, &LB[0][ldsOff1]);
        }
        __syncthreads();

        for (int t = 0; t < 32; ++t) {
            const int cur = t & 1;
            float4 n0, n1, n2, n3;
            if (t + 2 < 32) {   // issue A(t+2) loads (2-deep)
                const long kc = (long)(t + 2) << 5;
                n0 = *(const float4*)(Aq + srcA0 + kc);
                n1 = *(const float4*)(Aq + srcA0 + kc + 4);
                n2 = *(const float4*)(Aq + srcA1 + kc);
                n3 = *(const float4*)(Aq + srcA1 + kc + 4);
            }
            if (t + 1 < 32) {
                const long kc = (long)(t + 1) << 5;
                gld_lds16(Bb + offB0 + kc, &LB[cur ^ 1][ldsOff0]);
                gld_lds16(Bb + offB1 + kc, &LB[cur ^ 1][ldsOff1]);
            }
            f16x8 a[8], b[4];
#pragma unroll
            for (int m = 0; m < 8; ++m) {
                int r = rA0 + m * 16;
                a[m] = *(const f16x8*)(&LA[cur][r * 32 + ((g ^ SWZ(r)) << 3)]);
            }
#pragma unroll
            for (int n = 0; n < 4; ++n) {
                int r = rB0 + n * 16;
                b[n] = *(const f16x8*)(&LB[cur][r * 32 + ((g ^ SWZ(r)) << 3)]);
            }
            __builtin_amdgcn_s_setprio(1);
#pragma unroll
            for (int m = 0; m < 8; ++m)
#pragma unroll
                for (int n = 0; n < 4; ++n)
                    acc[m][n] = __builtin_amdgcn_mfma_f32_16x16x32_f16(a[m], b[n], acc[m][n], 0, 0, 0);
            __builtin_amdgcn_s_setprio(0);
            if (t + 1 < 32) {   // write pending A(t+1), shift prefetch
                f16x8 h0 = {(f16)p0.x, (f16)p0.y, (f16)p0.z, (f16)p0.w,
                            (f16)p1.x, (f16)p1.y, (f16)p1.z, (f16)p1.w};
                f16x8 h1 = {(f16)p2.x, (f16)p2.y, (f16)p2.z, (f16)p2.w,
                            (f16)p3.x, (f16)p3.y, (f16)p3.z, (f16)p3.w};
                *(f16x8*)(&LA[cur ^ 1][wA0]) = h0;
                *(f16x8*)(&LA[cur ^ 1][wA1]) = h1;
                p0 = n0; p1 = n1; p2 = n2; p3 = n3;
            }
            __syncthreads();
        }
        const int row0 = by * 256 + (w & 1) * 128 + (lane >> 4) * 4;
        const int col0 = bx * 256 + (w >> 1) * 64 + (lane & 15);
#pragma unroll
        for (int m = 0; m < 8; ++m)
#pragma unroll
            for (int r = 0; r < 4; ++r) {
                long row = row0 + m * 16 + r;
#pragma unroll
                for (int n = 0; n < 4; ++n)
                    qUh[row * D_DIM + col0 + n * 16] = (f16)acc[m][n][r];
            }
    } else {
        // ---------------- cast q2 (2 tiles per block) ----------------
        int hf = tid >> 8, t2 = tid & 255;
        f16 (*tr)[72] = (f16(*)[72])(SM + hf * 4608);
        int p = (blockIdx.y - 128) * 4 + blockIdx.x;  // 0..4095
        int tile = p * 2 + hf;                        // 0..8191
        int b = tile >> 7, rem = tile & 127;
        int d0 = (rem & 15) * 64, t0 = (rem >> 4) * 64;
        const float* S = q2 + ((size_t)b * T_DIM + t0) * D_DIM + d0;
        f16* Dr = q2h + ((size_t)b * T_DIM + t0) * D_DIM + d0;
        int rr = t2 >> 4, cc = (t2 & 15) * 4;
#pragma unroll
        for (int i = 0; i < 4; ++i) {
            int r = rr + i * 16;
            float4 v = *(const float4*)(S + (size_t)r * D_DIM + cc);
            f16x4 h = {(f16)v.x, (f16)v.y, (f16)v.z, (f16)v.w};
            *(f16x4*)(Dr + (size_t)r * D_DIM + cc) = h;
            tr[cc + 0][r] = h[0];
            tr[cc + 1][r] = h[1];
            tr[cc + 2][r] = h[2];
            tr[cc + 3][r] = h[3];
        }
        __syncthreads();
        f16* Dt = q2ht + ((size_t)b * D_DIM + d0) * T_DIM + t0;
        int r2 = t2 >> 3, c8 = (t2 & 7) * 8;
#pragma unroll
        for (int i = 0; i < 2; ++i) {
            int d = r2 + i * 32;
            f16x8 vv = *(const f16x8*)(&tr[d][c8]);
            *(f16x8*)(Dt + (size_t)d * T_DIM + c8) = vv;
        }
    }
}

// ===========================================================================
// D3 (R7-proven, unchanged): att GEMM (qUh @ q2h^T, f16 gld_lds both).
// Epilogue: relu, rowP/colP partials, P2', P1'.  grid (2,2,64)
// ===========================================================================
__global__ __launch_bounds__(512, 2) void k_att3(const f16* __restrict__ qUh,
                                                 const f16* __restrict__ q2h,
                                                 f16* __restrict__ P2,
                                                 f16* __restrict__ P1,
                                                 float2* __restrict__ rowP,
                                                 float2* __restrict__ colP) {
    __shared__ __align__(16) f16 LA[2][8192];
    __shared__ __align__(16) f16 LB[2][8192];
    const int tid = threadIdx.x;
    const int lane = tid & 63, w = tid >> 6;

    int o = blockIdx.x + 2 * (blockIdx.y + 2 * blockIdx.z);  // nwg=256
    int fl = (o & 7) * 32 + (o >> 3);
    const int bx = fl & 1, by = (fl >> 1) & 1, zb = fl >> 2;

    const f16* Ab = qUh + (long)(zb * 512 + by * 256) * D_DIM;
    const f16* Bb = q2h + (long)zb * TD + (long)(bx * 256) * D_DIM;

    const int r0 = tid >> 2, j0 = tid & 3;
    const int r1 = r0 + 128;
    const long offA0 = (long)r0 * D_DIM + (j0 ^ SWZ(r0)) * 8;
    const long offA1 = (long)r1 * D_DIM + (j0 ^ SWZ(r1)) * 8;
    const int ldsOff0 = w * 512, ldsOff1 = 4096 + w * 512;
    const int g = lane >> 4;
    const int rA0 = (w & 1) * 128 + (lane & 15);
    const int rB0 = (w >> 1) * 64 + (lane & 15);

    f32x4 acc[8][4] = {};

    gld_lds16(Ab + offA0, &LA[0][ldsOff0]);
    gld_lds16(Ab + offA1, &LA[0][ldsOff1]);
    gld_lds16(Bb + offA0, &LB[0][ldsOff0]);
    gld_lds16(Bb + offA1, &LB[0][ldsOff1]);
    __syncthreads();

    for (int t = 0; t < 32; ++t) {
        const int cur = t & 1;
        if (t + 1 < 32) {
            const long kt = (long)(t + 1) << 5;
            gld_lds16(Ab + offA0 + kt, &LA[cur ^ 1][ldsOff0]);
            gld_lds16(Ab + offA1 + kt, &LA[cur ^ 1][ldsOff1]);
            gld_lds16(Bb + offA0 + kt, &LB[cur ^ 1][ldsOff0]);
            gld_lds16(Bb + offA1 + kt, &LB[cur ^ 1][ldsOff1]);
        }
        f16x8 a[8], b[4];
#pragma unroll
        for (int m = 0; m < 8; ++m) {
            int r = rA0 + m * 16;
            a[m] = *(const f16x8*)(&LA[cur][r * 32 + ((g ^ SWZ(r)) << 3)]);
        }
#pragma unroll
        for (int n = 0; n < 4; ++n) {
            int r = rB0 + n * 16;
            b[n] = *(const f16x8*)(&LB[cur][r * 32 + ((g ^ SWZ(r)) << 3)]);
        }
        __builtin_amdgcn_s_setprio(1);
#pragma unroll
        for (int m = 0; m < 8; ++m)
#pragma unroll
            for (int n = 0; n < 4; ++n)
                acc[m][n] = __builtin_amdgcn_mfma_f32_16x16x32_f16(a[m], b[n], acc[m][n], 0, 0, 0);
        __builtin_amdgcn_s_setprio(0);
        __syncthreads();
    }

    // relu
#pragma unroll
    for (int m = 0; m < 8; ++m)
#pragma unroll
        for (int n = 0; n < 4; ++n)
#pragma unroll
            for (int r = 0; r < 4; ++r)
                acc[m][n][r] = fmaxf(acc[m][n][r], 0.0f);

    // ---- softmax partials (LA reused as scratch) ----
    float* redR = (float*)(&LA[0][0]);   // [256][4][2]
    float* redC = redR + 2048;           // [2][256][2]
    float* rowM = redC + 1024;           // [256]
    float* colM = rowM + 256;            // [256]
    const int h = w & 1, cw = w >> 1;
#pragma unroll
    for (int m = 0; m < 8; ++m)
#pragma unroll
        for (int r = 0; r < 4; ++r) {
            float mx = fmaxf(fmaxf(acc[m][0][r], acc[m][1][r]),
                             fmaxf(acc[m][2][r], acc[m][3][r]));
            mx = fmaxf(mx, __shfl_xor(mx, 1));
            mx = fmaxf(mx, __shfl_xor(mx, 2));
            mx = fmaxf(mx, __shfl_xor(mx, 4));
            mx = fmaxf(mx, __shfl_xor(mx, 8));
            float sm = __expf(acc[m][0][r] - mx) + __expf(acc[m][1][r] - mx)
                     + __expf(acc[m][2][r] - mx) + __expf(acc[m][3][r] - mx);
            sm += __shfl_xor(sm, 1);
            sm += __shfl_xor(sm, 2);
            sm += __shfl_xor(sm, 4);
            sm += __shfl_xor(sm, 8);
            if ((lane & 15) == 0) {
                int lr = m * 16 + (lane >> 4) * 4 + r;
                redR[((h * 128 + lr) * 4 + cw) * 2 + 0] = mx;
                redR[((h * 128 + lr) * 4 + cw) * 2 + 1] = sm;
            }
        }
#pragma unroll
    for (int n = 0; n < 4; ++n) {
        float mx = acc[0][n][0];
#pragma unroll
        for (int m = 0; m < 8; ++m)
#pragma unroll
            for (int r = 0; r < 4; ++r) mx = fmaxf(mx, acc[m][n][r]);
        mx = fmaxf(mx, __shfl_xor(mx, 16));
        mx = fmaxf(mx, __shfl_xor(mx, 32));
        float sm = 0.f;
#pragma unroll
        for (int m = 0; m < 8; ++m)
#pragma unroll
            for (int r = 0; r < 4; ++r) sm += __expf(acc[m][n][r] - mx);
        sm += __shfl_xor(sm, 16);
        sm += __shfl_xor(sm, 32);
        if (lane < 16) {
            int c = cw * 64 + n * 16 + lane;
            redC[(h * 256 + c) * 2 + 0] = mx;
            redC[(h * 256 + c) * 2 + 1] = sm;
        }
    }
    __syncthreads();
    if (tid < 256) {
        float M = -1e30f, S = 0.f;
#pragma unroll
        for (int i = 0; i < 4; ++i) {
            float m_ = redR[(tid * 4 + i) * 2 + 0];
            float s_ = redR[(tid * 4 + i) * 2 + 1];
            float nm = fmaxf(M, m_);
            S = S * __expf(M - nm) + s_ * __expf(m_ - nm);
            M = nm;
        }
        rowP[(long)bx * PSTR + (long)zb * 512 + by * 256 + tid] = make_float2(M, S);
        rowM[tid] = M;
    } else {
        int c = tid - 256;
        float m0_ = redC[c * 2 + 0], s0_ = redC[c * 2 + 1];
        float m1_ = redC[(256 + c) * 2 + 0], s1_ = redC[(256 + c) * 2 + 1];
        float M = fmaxf(m0_, m1_);
        float S = s0_ * __expf(m0_ - M) + s1_ * __expf(m1_ - M);
        colP[(long)by * PSTR + (long)zb * 512 + bx * 256 + c] = make_float2(M, S);
        colM[c] = M;
    }
    __syncthreads();

    // ---- P2'[t][s] = f16(exp(att - M_rowhalf)) ----
    f16* P2b = P2 + (long)zb * TT;
#pragma unroll
    for (int m = 0; m < 8; ++m)
#pragma unroll
        for (int r = 0; r < 4; ++r) {
            int Lr = h * 128 + m * 16 + (lane >> 4) * 4 + r;
            float M = rowM[Lr];
            long base = (long)(by * 256 + Lr) * T_DIM + bx * 256;
#pragma unroll
            for (int n = 0; n < 4; ++n) {
                int c = cw * 64 + n * 16 + (lane & 15);
                P2b[base + c] = (f16)__expf(acc[m][n][r] - M);
            }
        }
    // ---- P1'[s][t] = f16(exp(att - M_colhalf)), 8B column stores ----
    f16* P1b = P1 + (long)zb * TT;
#pragma unroll
    for (int m = 0; m < 8; ++m) {
        int Lt = h * 128 + m * 16 + (lane >> 4) * 4;
#pragma unroll
        for (int n = 0; n < 4; ++n) {
            int Lc = cw * 64 + n * 16 + (lane & 15);
            float M = colM[Lc];
            f16x4 v = {(f16)__expf(acc[m][n][0] - M), (f16)__expf(acc[m][n][1] - M),
                       (f16)__expf(acc[m][n][2] - M), (f16)__expf(acc[m][n][3] - M)};
            *(f16x4*)(&P1b[(long)(bx * 256 + Lc) * T_DIM + by * 256 + Lt]) = v;
        }
    }
}

// ===========================================================================
// D4: both align GEMMs, 2-DEEP A prefetch. z<64: q2align; z>=64: q1align.
// A reg-staged f16 with rescale factor exp(M_half - M_global); * 1/S epilogue.
// grid (4,2,128)
// ===========================================================================
__global__ __launch_bounds__(512, 2) void k_align(
        const f16* __restrict__ P2, const f16* __restrict__ q2ht,
        const float2* __restrict__ rowP, float* __restrict__ outQ2,
        const f16* __restrict__ P1, const f16* __restrict__ q1ht,
        const float2* __restrict__ colP, float* __restrict__ outQ1) {
    __shared__ __align__(16) f16 LA[2][8192];
    __shared__ __align__(16) f16 LB[2][8192];
    const int tid = threadIdx.x;
    const int lane = tid & 63, w = tid >> 6;

    int o = blockIdx.x + 4 * (blockIdx.y + 2 * blockIdx.z);  // nwg=1024
    int fl = (o & 7) * 128 + (o >> 3);
    const int bx = fl & 3, by = (fl >> 2) & 1, z = fl >> 3;
    const int zb = z & 63;

    const f16* P  = (z < 64) ? P2 : P1;
    const f16* Bt = (z < 64) ? q2ht : q1ht;
    const float2* sp = ((z < 64) ? rowP : colP) + (long)zb * 512;
    float* out = ((z < 64) ? outQ2 : outQ1) + (long)zb * TD;

    const f16* Ab = P + (long)zb * TT + (long)(by * 256) * T_DIM;
    const f16* Bb = Bt + (long)zb * TD + (long)(bx * 256) * T_DIM;

    const int r0 = tid >> 2, j0 = tid & 3;
    const int r1 = r0 + 128;
    // rescale factors: fac(r, k-half) = exp(M_half - M_global)
    float2 pa0 = sp[by * 256 + r0], pb0 = sp[PSTR + by * 256 + r0];
    float M0 = fmaxf(pa0.x, pb0.x);
    f16 f00 = (f16)__expf(pa0.x - M0), f01 = (f16)__expf(pb0.x - M0);
    float2 pa1 = sp[by * 256 + r1], pb1 = sp[PSTR + by * 256 + r1];
    float M1 = fmaxf(pa1.x, pb1.x);
    f16 f10 = (f16)__expf(pa1.x - M1), f11 = (f16)__expf(pb1.x - M1);

    const long srcA0 = (long)r0 * T_DIM + j0 * 8;
    const long srcA1 = (long)r1 * T_DIM + j0 * 8;
    const int wA0 = r0 * 32 + ((j0 ^ SWZ(r0)) << 3);
    const int wA1 = r1 * 32 + ((j0 ^ SWZ(r1)) << 3);
    const long offB0 = (long)r0 * T_DIM + (j0 ^ SWZ(r0)) * 8;
    const long offB1 = (long)r1 * T_DIM + (j0 ^ SWZ(r1)) * 8;
    const int ldsOff0 = w * 512, ldsOff1 = 4096 + w * 512;
    const int g = lane >> 4;
    const int rA0 = (w & 1) * 128 + (lane & 15);
    const int rB0 = (w >> 1) * 64 + (lane & 15);

    f32x4 acc[8][4] = {};
    f16x8 p0, p1;   // pending A(t+1), unscaled
    {
        f16x8 a0 = *(const f16x8*)(Ab + srcA0);
        f16x8 a1 = *(const f16x8*)(Ab + srcA1);
#pragma unroll
        for (int i = 0; i < 8; ++i) { a0[i] *= f00; a1[i] *= f10; }
        *(f16x8*)(&LA[0][wA0]) = a0;
        *(f16x8*)(&LA[0][wA1]) = a1;
        p0 = *(const f16x8*)(Ab + srcA0 + 32);
        p1 = *(const f16x8*)(Ab + srcA1 + 32);
        gld_lds16(Bb + offB0, &LB[0][ldsOff0]);
        gld_lds16(Bb + offB1, &LB[0][ldsOff1]);
    }
    __syncthreads();

    for (int t = 0; t < 16; ++t) {
        const int cur = t & 1;
        f16x8 n0, n1;
        if (t + 2 < 16) {   // A(t+2), 2-deep
            const long kc = (long)(t + 2) << 5;
            n0 = *(const f16x8*)(Ab + srcA0 + kc);
            n1 = *(const f16x8*)(Ab + srcA1 + kc);
        }
        if (t + 1 < 16) {
            const long kc = (long)(t + 1) << 5;
            gld_lds16(Bb + offB0 + kc, &LB[cur ^ 1][ldsOff0]);
            gld_lds16(Bb + offB1 + kc, &LB[cur ^ 1][ldsOff1]);
        }
        f16x8 a[8], b[4];
#pragma unroll
        for (int m = 0; m < 8; ++m) {
            int r = rA0 + m * 16;
            a[m] = *(const f16x8*)(&LA[cur][r * 32 + ((g ^ SWZ(r)) << 3)]);
        }
#pragma unroll
        for (int n = 0; n < 4; ++n) {
            int r = rB0 + n * 16;
            b[n] = *(const f16x8*)(&LB[cur][r * 32 + ((g ^ SWZ(r)) << 3)]);
        }
        __builtin_amdgcn_s_setprio(1);
#pragma unroll
        for (int m = 0; m < 8; ++m)
#pragma unroll
            for (int n = 0; n < 4; ++n)
                acc[m][n] = __builtin_amdgcn_mfma_f32_16x16x32_f16(a[m], b[n], acc[m][n], 0, 0, 0);
        __builtin_amdgcn_s_setprio(0);
        if (t + 1 < 16) {   // write pending A(t+1) scaled by its k-half factor
            f16 fa = ((t + 1) & 8) ? f01 : f00;
            f16 fb = ((t + 1) & 8) ? f11 : f10;
            f16x8 h0 = p0, h1 = p1;
#pragma unroll
            for (int i = 0; i < 8; ++i) { h0[i] *= fa; h1[i] *= fb; }
            *(f16x8*)(&LA[cur ^ 1][wA0]) = h0;
            *(f16x8*)(&LA[cur ^ 1][wA1]) = h1;
            p0 = n0; p1 = n1;
        }
        __syncthreads();
    }

    const int row0 = by * 256 + (w & 1) * 128 + (lane >> 4) * 4;
    const int col0 = bx * 256 + (w >> 1) * 64 + (lane & 15);
#pragma unroll
    for (int m = 0; m < 8; ++m)
#pragma unroll
        for (int r = 0; r < 4; ++r) {
            int row = row0 + m * 16 + r;
            float2 pa = sp[row], pb = sp[PSTR + row];
            float M = fmaxf(pa.x, pb.x);
            float S = pa.y * __expf(pa.x - M) + pb.y * __expf(pb.x - M);
            float inv = 1.0f / S;
#pragma unroll
            for (int n = 0; n < 4; ++n)
                out[(long)row * D_DIM + col0 + n * 16] = acc[m][n][r] * inv;
        }
}

// ===========================================================================
extern "C" void kernel_launch(void* const* d_in, const int* in_sizes, int n_in,
                              void* d_out, int out_size, void* d_ws, size_t ws_size,
                              hipStream_t stream) {
    const float* q1 = (const float*)d_in[0];
    const float* q2 = (const float*)d_in[1];
    const float* U  = (const float*)d_in[2];
    float* out = (float*)d_out;

    const size_t BTD = (size_t)B_DIM * TD;   // 33.55M
    const size_t DD  = (size_t)D_DIM * D_DIM;
    const size_t BTT = (size_t)B_DIM * TT;   // 16.78M

    const size_t need = (4 * BTD + DD) * 2      // q1ht,q2h,q2ht,qUh + Uht
                      + 2 * BTT * 2             // P2', P1'
                      + 4 * (size_t)PSTR * sizeof(float2);
    if (need > ws_size) return;

    f16* q1ht = (f16*)d_ws;
    f16* q2h  = q1ht + BTD;
    f16* q2ht = q2h  + BTD;
    f16* Uht  = q2ht + BTD;
    f16* qUh  = Uht  + DD;
    f16* P2   = qUh  + BTD;
    f16* P1   = P2   + BTT;
    float2* rowP = (float2*)(P1 + BTT);   // [2][PSTR]
    float2* colP = rowP + 2 * (size_t)PSTR;

    // D1: cast q1 -> q1ht, U -> Uht (R7-proven small-LDS streaming)
    k_d1<<<dim3(16, 8, 65), 256, 0, stream>>>(q1, q1ht, U, Uht);
    // D2: GEMM1 (2-deep A prefetch) || cast q2 -> q2h,q2ht
    k_d2<<<dim3(4, 128 + 1024), 512, 0, stream>>>(q1, Uht, qUh, q2, q2h, q2ht);
    // D3: att GEMM -> partials + P2' + P1'
    k_att3<<<dim3(2, 2, 64), 512, 0, stream>>>(qUh, q2h, P2, P1, rowP, colP);
    // D4: both align GEMMs (2-deep A prefetch)
    k_align<<<dim3(4, 2, 128), 512, 0, stream>>>(
        P2, q2ht, rowP, out + BTD, P1, q1ht, colP, out);
}